// Round 3
// baseline (406.661 us; speedup 1.0000x reference)
//
#include <hip/hip_runtime.h>
#include <hip/hip_bf16.h>

// Transformer block: LN1 -> QKV -> MHA(16 heads, hd=64) -> out-proj + resid
//                    -> LN2 -> FFN(4x, ReLU) + resid
// B=2, S=2048, D=1024, H=16, hd=64, F=4096. M = B*S = 4096.
// fp32 buffers in/out; bf16 intermediates (fp32 accumulation).
//
// Round 13: attn is latency-bound: 2 waves/SIMD (grid 512 blocks = 2/CU)
// can't hide the serial softmax chain (fmax tree -> shfl -> 32 quarter-rate
// exp2 -> pack); VALUBusy stuck at 48%, MfmaUtil 25%. Round-1 showed more
// blocks (TQ=64) doubles staging and regresses. This round: split j INSIDE
// the block - 512 threads / 8 waves; waves 0-3 take even j-tiles, 4-7 odd,
// each group double-buffers its own K/V in LDS (70KB, 2 blocks/CU -> 16
// waves/CU = 4/SIMD, 2x latency hiding; staging per K/V element still once
// per block). Epilogue: group 1 parks (O,m,l) in LDS (over dead K/V bufs),
// group 0 does the 2-way online-softmax merge and stores.
// GEMM pipeline unchanged from round 9 (BK=64 + XOR chunk swizzle).

using bf16 = __hip_bfloat16;
typedef short bf16x8 __attribute__((ext_vector_type(8)));
typedef short bf16x4v __attribute__((ext_vector_type(4)));
typedef float f32x4 __attribute__((ext_vector_type(4)));

#if defined(__has_builtin)
#  if __has_builtin(__builtin_amdgcn_mfma_f32_16x16x16bf16_1k)
#    define HAVE_MFMA_K16 1
#  endif
#  if __has_builtin(__builtin_amdgcn_exp2f)
#    define EXP2F(x) __builtin_amdgcn_exp2f(x)
#  endif
#endif
#ifndef EXP2F
#  define EXP2F(x) __expf(0.6931471805599453f * (x))
#endif

__device__ __forceinline__ float toF(float v) { return v; }
__device__ __forceinline__ float toF(bf16 v) { return __bfloat162float(v); }
__device__ __forceinline__ void storeF(float* p, float v) { *p = v; }
__device__ __forceinline__ void storeF(bf16* p, float v) { *p = __float2bfloat16(v); }

__device__ __forceinline__ float waveReduceSum(float v) {
    #pragma unroll
    for (int o = 32; o > 0; o >>= 1) v += __shfl_down(v, o, 64);
    return v;
}

__device__ __forceinline__ void async16(const bf16* g, bf16* l) {
    __builtin_amdgcn_global_load_lds(
        (const __attribute__((address_space(1))) unsigned int*)g,
        (__attribute__((address_space(3))) unsigned int*)l,
        16, 0, 0);
}

__device__ __forceinline__ unsigned short bf16bits(float x) {
    union { bf16 h; unsigned short u; } e; e.h = __float2bfloat16(x);
    return e.u;
}

// ---------------- fused weight transpose + cast (all 6 weights) ------------
__global__ __launch_bounds__(256) void transpose_all(
        const float* __restrict__ wq, const float* __restrict__ wk,
        const float* __restrict__ wv, const float* __restrict__ wo,
        const float* __restrict__ w1, const float* __restrict__ w2,
        bf16* __restrict__ wqkvT, bf16* __restrict__ woT,
        bf16* __restrict__ w1T, bf16* __restrict__ w2T) {
    __shared__ float t[32][33];
    const int tI = blockIdx.x;
    const float* in; bf16* outT; int R, C, tl;
    if (tI < 4096) {
        const int seg = tI >> 10; tl = tI & 1023; R = 1024; C = 1024;
        in = (seg == 0) ? wq : (seg == 1) ? wk : (seg == 2) ? wv : wo;
        outT = (seg == 3) ? woT : wqkvT + (size_t)seg * 1024 * 1024;
    } else if (tI < 8192) {
        tl = tI - 4096; in = w1; outT = w1T; R = 1024; C = 4096;
    } else {
        tl = tI - 8192; in = w2; outT = w2T; R = 4096; C = 1024;
    }
    const int tc = C >> 5;
    const int c0 = (tl % tc) * 32, r0 = (tl / tc) * 32;
    const int lx = threadIdx.x & 31, ly = threadIdx.x >> 5;
    #pragma unroll
    for (int i = 0; i < 32; i += 8)
        t[ly + i][lx] = in[(size_t)(r0 + ly + i) * C + c0 + lx];
    __syncthreads();
    #pragma unroll
    for (int i = 0; i < 32; i += 8)
        outT[(size_t)(c0 + ly + i) * R + r0 + lx] = __float2bfloat16(t[lx][ly + i]);
}

// ---------------- LayerNorm: InT x -> bf16 out ----------------
template <typename InT>
__global__ __launch_bounds__(256) void ln_kernel(const InT* __restrict__ x,
                                                 const float* __restrict__ g,
                                                 const float* __restrict__ b,
                                                 bf16* __restrict__ out, int D) {
    const int row = blockIdx.x;
    const InT* xr = x + (size_t)row * D;
    float s = 0.f, s2 = 0.f;
    for (int i = threadIdx.x; i < D; i += 256) {
        float v = toF(xr[i]);
        s += v; s2 += v * v;
    }
    __shared__ float ws[4], ws2[4];
    int lane = threadIdx.x & 63, wid = threadIdx.x >> 6;
    s = waveReduceSum(s); s2 = waveReduceSum(s2);
    if (lane == 0) { ws[wid] = s; ws2[wid] = s2; }
    __syncthreads();
    float ts = ws[0] + ws[1] + ws[2] + ws[3];
    float ts2 = ws2[0] + ws2[1] + ws2[2] + ws2[3];
    float mean = ts / D;
    float var = ts2 / D - mean * mean;
    float rstd = rsqrtf(var + 1e-5f);
    bf16* outr = out + (size_t)row * D;
    for (int i = threadIdx.x; i < D; i += 256) {
        float v = (toF(xr[i]) - mean) * rstd * g[i] + b[i];
        outr[i] = __float2bfloat16(v);
    }
}

// ---------------- MFMA GEMM: C = act(A @ BT^T + bias) [+ resid] ------------
// BK=64, XOR-swizzled LDS (chunk c of row r stored at slot c^(r&7)).
template <int BM, typename OutT, typename ResidT, bool RELU, bool HAS_RESID, bool BIAS3>
__global__ __launch_bounds__(256) void gemm_mfma(const bf16* __restrict__ A,
                                                 const bf16* __restrict__ BT,
                                                 const float* __restrict__ bias,
                                                 const float* __restrict__ biasK,
                                                 const float* __restrict__ biasV,
                                                 const ResidT* __restrict__ resid,
                                                 OutT* __restrict__ C,
                                                 int M, int N, int K) {
    constexpr int BK = 64;
    constexpr int MI = BM / 32;
    constexpr int AROWS = BM / 4;
    constexpr int ASEC = AROWS / 8;
    __shared__ bf16 As[BM][BK];      // row stride 128 B
    __shared__ bf16 Bs[128][BK];
    const int tid = threadIdx.x, lane = tid & 63, wid = tid >> 6;
    const int m0 = blockIdx.y * BM, n0 = blockIdx.x * 128;
    const int wm = (BM == 128) ? (wid >> 1) * 64 : (wid & 1) * 32;
    const int wn = (BM == 128) ? (wid & 1) * 64 : (wid >> 1) * 64;

    f32x4 acc[MI][4] = {};

    const int srow = lane >> 3;
    const int scol = ((lane & 7) ^ srow) * 8;
    const bf16* Abase = A + (size_t)(m0 + wid * AROWS + srow) * K + scol;
    const bf16* Bbase = BT + (size_t)(n0 + wid * 32 + srow) * K + scol;

    const int fr = lane & 15;
    const int kg = lane >> 4;

    for (int k0 = 0; k0 < K; k0 += BK) {
        #pragma unroll
        for (int s = 0; s < ASEC; ++s)
            async16(Abase + (size_t)(s * 8) * K + k0, &As[wid * AROWS + s * 8][0]);
        #pragma unroll
        for (int s = 0; s < 4; ++s)
            async16(Bbase + (size_t)(s * 8) * K + k0, &Bs[wid * 32 + s * 8][0]);
        __syncthreads();

        #pragma unroll
        for (int ks = 0; ks < 2; ++ks) {
            const int pc = ((ks * 4 + kg) ^ (fr & 7)) * 16;
            bf16x8 aF[MI], bF[4];
            #pragma unroll
            for (int i = 0; i < MI; ++i)
                aF[i] = *(const bf16x8*)((const char*)&As[0][0]
                         + (size_t)(wm + i * 16 + fr) * 128 + pc);
            #pragma unroll
            for (int j = 0; j < 4; ++j)
                bF[j] = *(const bf16x8*)((const char*)&Bs[0][0]
                         + (size_t)(wn + j * 16 + fr) * 128 + pc);
            #pragma unroll
            for (int i = 0; i < MI; ++i)
                #pragma unroll
                for (int j = 0; j < 4; ++j)
                    acc[i][j] = __builtin_amdgcn_mfma_f32_16x16x32_bf16(
                        aF[i], bF[j], acc[i][j], 0, 0, 0);
        }
        __syncthreads();
    }

    const int col_l = lane & 15, row_l = (lane >> 4) * 4;
    #pragma unroll
    for (int j = 0; j < 4; ++j) {
        const int col = n0 + wn + j * 16 + col_l;
        float bvv;
        if (BIAS3) {
            const float* bp = (col < 1024) ? bias : ((col < 2048) ? biasK : biasV);
            bvv = bp[col & 1023];
        } else {
            bvv = bias[col];
        }
        #pragma unroll
        for (int i = 0; i < MI; ++i) {
            #pragma unroll
            for (int r = 0; r < 4; ++r) {
                const int row = m0 + wm + i * 16 + row_l + r;
                float v = acc[i][j][r] + bvv;
                if (RELU) v = fmaxf(v, 0.f);
                if (HAS_RESID) v += toF(resid[(size_t)row * N + col]);
                storeF(&C[(size_t)row * N + col], v);
            }
        }
    }
}

// ---------------- MFMA flash attention, S^T formulation ---------------------
// TQ=128, 512 threads / 8 waves. Waves 0-3 (group 0) do even j-tiles,
// waves 4-7 (group 1) odd j-tiles; per-group double-buffered K/V staging
// (T14 issue-early/write-late). 2-way online-softmax merge in epilogue.
#if HAVE_MFMA_K16
__global__ __launch_bounds__(512, 4) void attn_mfma(const bf16* __restrict__ qkv,
                                                    const int* __restrict__ mask,
                                                    bf16* __restrict__ outp,
                                                    int B, int S, int LD) {
    const int q0 = blockIdx.x * 128;
    const int h = blockIdx.y, b = blockIdx.z;
    const int Do = 1024;
    const int tid = threadIdx.x, lane = tid & 63, wid = tid >> 6;
    const int g = wid >> 2;          // j-parity group
    const int wl = wid & 3;          // wave-in-group: q-strip
    const int stid = tid & 255;      // staging id within group
    const int n = lane & 15, kg = lane >> 4;

    // LDS: [0,33792) K tiles (4 slots of [64][66] bf16, slot = g*2+buf)
    //      [33792,68608) V^T tiles (4 slots of [64][68] bf16)
    //      [68608,70656) mask bias f32 [4][64]; [70656,70672) sAny int [4]
    // Merge overlay (post-loop): po f32[128][65] @0, pm[128] @33280, pl[128] @33792.
    __shared__ __align__(16) char smem[70672];
    bf16* KsBase = (bf16*)smem;
    bf16* VtBase = (bf16*)(smem + 33792);
    float* MskfP = (float*)(smem + 68608);
    int* sAnyP   = (int*)(smem + 70656);

    // Q B-frags, pre-scaled by (1/sqrt(64))*log2(e); wave owns 32 q-rows.
    const float QSCALE = 0.125f * 1.4426950408889634f;
    bf16x8 qf[2][2];
    #pragma unroll
    for (int u = 0; u < 2; ++u) {
        const bf16* qp = qkv + ((size_t)(b * S + q0 + wl * 32 + u * 16 + n)) * LD + h * 64 + kg * 8;
        union { uint4 uu; bf16x8 v; unsigned short s[8]; } c[2];
        c[0].uu = *(const uint4*)qp;
        c[1].uu = *(const uint4*)(qp + 32);
        #pragma unroll
        for (int t = 0; t < 2; ++t) {
            #pragma unroll
            for (int i = 0; i < 8; ++i) {
                union { float f; unsigned int u2; } d;
                d.u2 = ((unsigned int)c[t].s[i]) << 16;
                c[t].s[i] = bf16bits(d.f * QSCALE);
            }
            qf[u][t] = c[t].v;
        }
    }

    f32x4 acc[2][4] = {};
    float m[2] = {-1e30f, -1e30f}, l[2] = {0.f, 0.f};

    const int sr = stid >> 2, sc = (stid & 3) * 16;
    const int jp = stid & 31, dg = (stid >> 5) * 8;
    const bf16* kbase = qkv + (size_t)(b * S) * LD + 1024 + h * 64;
    const bf16* vbase = qkv + (size_t)(b * S) * LD + 2048 + h * 64;

    // staged-tile registers (T14 issue-early / write-late)
    uint4 ka, kc, vau, vcu;
    int mz = 0;

    // prologue: issue group's tile-0 loads (global j-tile index = g)
    {
        const int j0 = g * 64;
        const bf16* kp = kbase + (size_t)(j0 + sr) * LD + sc;
        ka = *(const uint4*)kp;
        kc = *(const uint4*)(kp + 8);
        const bf16* vp = vbase + (size_t)(j0 + 2 * jp) * LD + dg;
        vau = *(const uint4*)vp;
        vcu = *(const uint4*)(vp + LD);
        if (stid < 64) mz = (mask[b * S + j0 + stid] == 0);
    }

    const int NT = S / 64;           // 32 j-tiles total; 16 per group
    for (int it = 0; it < NT / 2; ++it) {
        const int cur = it & 1;
        const int slot = g * 2 + cur;
        bf16* ksb = KsBase + slot * (64 * 66);
        bf16* vtb = VtBase + slot * (64 * 68);

        // ---- write staged tile into LDS (vmcnt wait lands here) ----
        {
            uint* kd = (uint*)((char*)ksb + sr * 132 + sc * 2);
            kd[0] = ka.x; kd[1] = ka.y; kd[2] = ka.z; kd[3] = ka.w;
            kd[4] = kc.x; kd[5] = kc.y; kd[6] = kc.z; kd[7] = kc.w;

            union { uint4 u4; unsigned short s[8]; } va, vc;
            va.u4 = vau; vc.u4 = vcu;
            #pragma unroll
            for (int i = 0; i < 8; ++i) {
                unsigned int pk = (unsigned int)va.s[i] | ((unsigned int)vc.s[i] << 16);
                *(unsigned int*)((char*)vtb + (size_t)(dg + i) * 136 + jp * 4) = pk;
            }
            if (stid < 64) {
                MskfP[slot * 64 + stid] = mz ? -1e9f : 0.f;
                unsigned long long bl = __ballot(mz);
                if (stid == 0) sAnyP[slot] = (bl != 0ull) ? 1 : 0;
            }
        }
        __syncthreads();

        // ---- issue next tile's global loads; latency hides under compute --
        {
            const int tg2 = 2 * (it + 1) + g;
            if (tg2 < NT) {
                const int j0 = tg2 * 64;
                const bf16* kp = kbase + (size_t)(j0 + sr) * LD + sc;
                ka = *(const uint4*)kp;
                kc = *(const uint4*)(kp + 8);
                const bf16* vp = vbase + (size_t)(j0 + 2 * jp) * LD + dg;
                vau = *(const uint4*)vp;
                vcu = *(const uint4*)(vp + LD);
                if (stid < 64) mz = (mask[b * S + j0 + stid] == 0);
            }
        }

        // ---- S^T = K @ Q^T (log2-scaled); K-frags read once ----
        f32x4 st[2][4] = {};
        #pragma unroll
        for (int ks = 0; ks < 2; ++ks) {
            #pragma unroll
            for (int jt = 0; jt < 4; ++jt) {
                union { uint u[4]; bf16x8 v; } kf;
                const uint* bp = (const uint*)((const char*)ksb
                                 + (size_t)(jt * 16 + n) * 132 + ks * 64 + kg * 16);
                kf.u[0] = bp[0]; kf.u[1] = bp[1]; kf.u[2] = bp[2]; kf.u[3] = bp[3];
                st[0][jt] = __builtin_amdgcn_mfma_f32_16x16x32_bf16(kf.v, qf[0][ks], st[0][jt], 0, 0, 0);
                st[1][jt] = __builtin_amdgcn_mfma_f32_16x16x32_bf16(kf.v, qf[1][ks], st[1][jt], 0, 0, 0);
            }
        }

        // ---- mask bias only when the tile actually has masked positions ---
        if (sAnyP[slot]) {
            #pragma unroll
            for (int u = 0; u < 2; ++u) {
                #pragma unroll
                for (int jt = 0; jt < 4; ++jt) {
                    f32x4 mb = *(const f32x4*)&MskfP[slot * 64 + jt * 16 + kg * 4];
                    #pragma unroll
                    for (int r = 0; r < 4; ++r) st[u][jt][r] += mb[r];
                }
            }
        }

        // ---- online softmax with defer-max (THR=8 in log2 domain) ---------
        float mx0 = st[0][0][0], mx1 = st[1][0][0];
        #pragma unroll
        for (int jt = 0; jt < 4; ++jt) {
            #pragma unroll
            for (int r = 0; r < 4; ++r) {
                mx0 = fmaxf(mx0, st[0][jt][r]);
                mx1 = fmaxf(mx1, st[1][jt][r]);
            }
        }
        mx0 = fmaxf(mx0, __shfl_xor(mx0, 16, 64));
        mx0 = fmaxf(mx0, __shfl_xor(mx0, 32, 64));
        mx1 = fmaxf(mx1, __shfl_xor(mx1, 16, 64));
        mx1 = fmaxf(mx1, __shfl_xor(mx1, 32, 64));

        if (__any((mx0 > m[0] + 8.f) || (mx1 > m[1] + 8.f))) {
            float mxa[2] = {mx0, mx1};
            #pragma unroll
            for (int u = 0; u < 2; ++u) {
                float newm = fmaxf(m[u], mxa[u]);
                float alpha = EXP2F(m[u] - newm);
                m[u] = newm;
                l[u] *= alpha;
                #pragma unroll
                for (int dt = 0; dt < 4; ++dt)
                    #pragma unroll
                    for (int r = 0; r < 4; ++r) acc[u][dt][r] *= alpha;
            }
        }

        bf16x4v pf[2][4];
        #pragma unroll
        for (int u = 0; u < 2; ++u) {
            float ls = 0.f;
            #pragma unroll
            for (int jt = 0; jt < 4; ++jt) {
                union { unsigned short s[4]; bf16x4v v; } pk;
                #pragma unroll
                for (int r = 0; r < 4; ++r) {
                    union { float f; unsigned int u2; } p;
                    p.f = EXP2F(st[u][jt][r] - m[u]);
                    p.u2 &= 0xffff0000u;          // truncate to bf16
                    ls += p.f;                    // sum the truncated value
                    pk.s[r] = (unsigned short)(p.u2 >> 16);
                }
                pf[u][jt] = pk.v;
            }
            ls += __shfl_xor(ls, 16, 64);
            ls += __shfl_xor(ls, 32, 64);
            l[u] += ls;
        }

        // ---- O^T += V^T @ P^T; V-frags read once ----
        #pragma unroll
        for (int jt = 0; jt < 4; ++jt) {
            #pragma unroll
            for (int dt = 0; dt < 4; ++dt) {
                union { uint u[2]; bf16x4v v; } vf;
                const uint* vpp = (const uint*)((const char*)vtb
                                  + (size_t)(dt * 16 + n) * 136 + jt * 32 + kg * 8);
                vf.u[0] = vpp[0]; vf.u[1] = vpp[1];
                acc[0][dt] = __builtin_amdgcn_mfma_f32_16x16x16bf16_1k(vf.v, pf[0][jt], acc[0][dt], 0, 0, 0);
                acc[1][dt] = __builtin_amdgcn_mfma_f32_16x16x16bf16_1k(vf.v, pf[1][jt], acc[1][dt], 0, 0, 0);
            }
        }
    }

    // ---- epilogue: 2-way online-softmax merge across groups ----
    __syncthreads();                       // all K/V reads done; overlay safe
    float* po = (float*)smem;              // [128][65]
    float* pm = (float*)(smem + 33280);    // [128]
    float* pl = (float*)(smem + 33792);    // [128]
    if (g == 1) {
        #pragma unroll
        for (int u = 0; u < 2; ++u) {
            const int ql = wl * 32 + u * 16 + n;
            if (kg == 0) { pm[ql] = m[u]; pl[ql] = l[u]; }
            #pragma unroll
            for (int dt = 0; dt < 4; ++dt)
                #pragma unroll
                for (int r = 0; r < 4; ++r)
                    po[ql * 65 + dt * 16 + kg * 4 + r] = acc[u][dt][r];
        }
    }
    __syncthreads();
    if (g == 0) {
        #pragma unroll
        for (int u = 0; u < 2; ++u) {
            const int ql = wl * 32 + u * 16 + n;
            float m1 = pm[ql], l1 = pl[ql];
            float newm = fmaxf(m[u], m1);
            float a0 = EXP2F(m[u] - newm);
            float a1 = EXP2F(m1 - newm);
            float lt = l[u] * a0 + l1 * a1;
            float inv = (lt > 0.f) ? (1.f / lt) : 0.f;
            bf16* op = outp + ((size_t)(b * S + q0 + wl * 32 + u * 16 + n)) * Do + h * 64;
            #pragma unroll
            for (int dt = 0; dt < 4; ++dt) {
                union { unsigned short s[4]; uint2 u2; } w;
                #pragma unroll
                for (int r = 0; r < 4; ++r) {
                    float o1 = po[ql * 65 + dt * 16 + kg * 4 + r];
                    w.s[r] = bf16bits((acc[u][dt][r] * a0 + o1 * a1) * inv);
                }
                *(uint2*)(op + dt * 16 + kg * 4) = w.u2;
            }
        }
    }
}
#else
// Fallback (round-5 structure, 512 threads): 8 waves each own 16 q-rows;
// threads 0-255 stage the shared K/V tile.
__global__ __launch_bounds__(512) void attn_mfma(const bf16* __restrict__ qkv,
                                                 const int* __restrict__ mask,
                                                 bf16* __restrict__ outp,
                                                 int B, int S, int LD) {
    const int h = blockIdx.y, b = blockIdx.z;
    const int Do = 1024;
    const int tid = threadIdx.x, lane = tid & 63, wid = tid >> 6;
    const int n = lane & 15, kg = lane >> 4;
    const int q0 = blockIdx.x * 128;

    __shared__ bf16 Ks[64][66];
    __shared__ bf16 Vt[64][66];
    __shared__ bf16 Plds[8][16][66];
    __shared__ int  Msk[64];

    bf16x8 qf[2];
    {
        const bf16* qp = qkv + ((size_t)(b * S + q0 + wid * 16 + n)) * LD + h * 64 + kg * 8;
        union { uint4 u; bf16x8 v; } c0, c1;
        c0.u = *(const uint4*)qp;
        c1.u = *(const uint4*)(qp + 32);
        qf[0] = c0.v; qf[1] = c1.v;
    }

    f32x4 acc_o[4] = {};
    float m_r[4] = {-1e30f, -1e30f, -1e30f, -1e30f};
    float l_r[4] = {0.f, 0.f, 0.f, 0.f};

    const int sr = tid >> 2;
    const int sc = (tid & 3) * 16;
    const bf16* kbase = qkv + (size_t)(b * S) * LD + 1024 + h * 64;
    const bf16* vbase = qkv + (size_t)(b * S) * LD + 2048 + h * 64;

    for (int j0 = 0; j0 < S; j0 += 64) {
        __syncthreads();
        if (tid < 256) {
            const bf16* kp = kbase + (size_t)(j0 + sr) * LD + sc;
            uint4 ka = *(const uint4*)kp;
            uint4 kbv = *(const uint4*)(kp + 8);
            uint* kd = (uint*)((char*)&Ks[0][0] + sr * 132 + sc * 2);
            kd[0] = ka.x; kd[1] = ka.y; kd[2] = ka.z; kd[3] = ka.w;
            kd[4] = kbv.x; kd[5] = kbv.y; kd[6] = kbv.z; kd[7] = kbv.w;

            const bf16* vp = vbase + (size_t)(j0 + sr) * LD + sc;
            union { uint4 u[2]; unsigned short s[16]; } vv;
            vv.u[0] = *(const uint4*)vp;
            vv.u[1] = *(const uint4*)(vp + 8);
            #pragma unroll
            for (int i = 0; i < 16; ++i)
                *((unsigned short*)((char*)&Vt[0][0] + (size_t)(sc + i) * 132 + sr * 2)) = vv.s[i];

            if (tid < 64) Msk[tid] = mask[b * S + j0 + tid];
        }
        __syncthreads();

        f32x4 st[4] = {};
        #pragma unroll
        for (int ks = 0; ks < 2; ++ks) {
            #pragma unroll
            for (int jt = 0; jt < 4; ++jt) {
                union { uint u[4]; bf16x8 v; } bf;
                const uint* bp = (const uint*)((const char*)&Ks[0][0]
                                 + (size_t)(jt * 16 + n) * 132 + ks * 64 + kg * 16);
                bf.u[0] = bp[0]; bf.u[1] = bp[1]; bf.u[2] = bp[2]; bf.u[3] = bp[3];
                st[jt] = __builtin_amdgcn_mfma_f32_16x16x32_bf16(qf[ks], bf.v, st[jt], 0, 0, 0);
            }
        }

        int mk[4];
        #pragma unroll
        for (int jt = 0; jt < 4; ++jt) mk[jt] = Msk[jt * 16 + n];

        #pragma unroll
        for (int r = 0; r < 4; ++r) {
            float mx = -1e30f;
            #pragma unroll
            for (int jt = 0; jt < 4; ++jt) {
                float s = st[jt][r] * 0.125f;
                if (mk[jt] == 0) s = -1e9f;
                st[jt][r] = s;
                mx = fmaxf(mx, s);
            }
            #pragma unroll
            for (int o = 1; o < 16; o <<= 1) mx = fmaxf(mx, __shfl_xor(mx, o, 64));
            float newm = fmaxf(m_r[r], mx);
            float alpha = __expf(m_r[r] - newm);
            m_r[r] = newm;
            float ls = 0.f;
            #pragma unroll
            for (int jt = 0; jt < 4; ++jt) {
                float p = __expf(st[jt][r] - newm);
                ls += p;
                Plds[wid][kg * 4 + r][jt * 16 + n] = __float2bfloat16(p);
            }
            #pragma unroll
            for (int o = 1; o < 16; o <<= 1) ls += __shfl_xor(ls, o, 64);
            l_r[r] = l_r[r] * alpha + ls;
            #pragma unroll
            for (int dt = 0; dt < 4; ++dt) acc_o[dt][r] *= alpha;
        }

        __asm__ volatile("s_waitcnt lgkmcnt(0)" ::: "memory");

        #pragma unroll
        for (int ks = 0; ks < 2; ++ks) {
            union { uint u[4]; bf16x8 v; } af;
            const uint* ap = (const uint*)((const char*)&Plds[wid][0][0]
                             + (size_t)n * 132 + ks * 64 + kg * 16);
            af.u[0] = ap[0]; af.u[1] = ap[1]; af.u[2] = ap[2]; af.u[3] = ap[3];
            #pragma unroll
            for (int dt = 0; dt < 4; ++dt) {
                union { uint u[4]; bf16x8 v; } bf;
                const uint* bp = (const uint*)((const char*)&Vt[0][0]
                                 + (size_t)(dt * 16 + n) * 132 + ks * 64 + kg * 16);
                bf.u[0] = bp[0]; bf.u[1] = bp[1]; bf.u[2] = bp[2]; bf.u[3] = bp[3];
                acc_o[dt] = __builtin_amdgcn_mfma_f32_16x16x32_bf16(af.v, bf.v, acc_o[dt], 0, 0, 0);
            }
        }
    }

    #pragma unroll
    for (int r = 0; r < 4; ++r) {
        float inv = (l_r[r] > 0.f) ? (1.f / l_r[r]) : 0.f;
        bf16* op = outp + ((size_t)(b * S + q0 + wid * 16 + kg * 4 + r)) * Do + h * 64 + n;
        #pragma unroll
        for (int dt = 0; dt < 4; ++dt)
            op[dt * 16] = __float2bfloat16(acc_o[dt][r] * inv);
    }
}
#endif

extern "C" void kernel_launch(void* const* d_in, const int* in_sizes, int n_in,
                              void* d_out, int out_size, void* d_ws, size_t ws_size,
                              hipStream_t stream) {
    const int B = 2, S = 2048, D = 1024, H = 16, F = 4096;
    const int M = B * S;  // 4096

    const float* x   = (const float*)d_in[0];
    const int*   mask= (const int*)  d_in[1];
    const float* wq  = (const float*)d_in[2];
    const float* bq  = (const float*)d_in[3];
    const float* wk  = (const float*)d_in[4];
    const float* bk  = (const float*)d_in[5];
    const float* wv  = (const float*)d_in[6];
    const float* bv  = (const float*)d_in[7];
    const float* wo  = (const float*)d_in[8];
    const float* bo  = (const float*)d_in[9];
    const float* g1  = (const float*)d_in[10];
    const float* be1 = (const float*)d_in[11];
    const float* g2  = (const float*)d_in[12];
    const float* be2 = (const float*)d_in[13];
    const float* w1  = (const float*)d_in[14];
    const float* bf1 = (const float*)d_in[15];
    const float* w2  = (const float*)d_in[16];
    const float* bf2 = (const float*)d_in[17];
    float* out = (float*)d_out;

    char* ws = (char*)d_ws;
    const size_t MB = 1024 * 1024;
    bf16* wqkvT = (bf16*)(ws + 0 * MB);            // [3072,1024]
    bf16* woT   = (bf16*)(ws + 6 * MB);
    bf16* w1T   = (bf16*)(ws + 8 * MB);
    bf16* w2T   = (bf16*)(ws + 16 * MB);
    bf16* xn    = (bf16*)(ws + 24 * MB);
    bf16* qkv   = (bf16*)(ws + 32 * MB);           // [4096,3072]
    bf16* att   = xn;                              // reuse
    // x2 (fp32 residual carrier) lives in d_out.

    const bool fullM = (ws_size >= 64 * MB);

    transpose_all<<<12288, 256, 0, stream>>>(wq, wk, wv, wo, w1, w2,
                                             wqkvT, woT, w1T, w2T);

    ln_kernel<float><<<M, 256, 0, stream>>>(x, g1, be1, xn, D);

    gemm_mfma<128, bf16, float, false, false, true><<<dim3(3072 / 128, M / 128), 256, 0, stream>>>(
        xn, wqkvT, bq, bk, bv, (const float*)nullptr, qkv, M, 3072, D);

    attn_mfma<<<dim3(S / 128, H, B), 512, 0, stream>>>(qkv, mask, att, B, S, 3072);

    gemm_mfma<64, float, float, false, true, false><<<dim3(D / 128, M / 64), 256, 0, stream>>>(
        att, woT, bo, nullptr, nullptr, x, out, M, D, D);

    if (fullM) {
        bf16* hid = (bf16*)(ws + 24 * MB);   // [4096,4096] at [24,56)
        bf16* xn2 = (bf16*)(ws + 56 * MB);   // [4096,1024] at [56,64)
        ln_kernel<float><<<M, 256, 0, stream>>>(out, g2, be2, xn2, D);
        gemm_mfma<128, bf16, float, true, false, false><<<dim3(F / 128, M / 128), 256, 0, stream>>>(
            xn2, w1T, bf1, nullptr, nullptr, (const float*)nullptr, hid, M, F, D);
        gemm_mfma<64, float, float, false, true, false><<<dim3(D / 128, M / 64), 256, 0, stream>>>(
            hid, w2T, bf2, nullptr, nullptr, out, out, M, D, F);
    } else {
        bf16* xn2 = (bf16*)(ws + 32 * MB);   // q-section reuse
        bf16* hid = (bf16*)(ws + 40 * MB);   // k+v sections, [2048,4096]
        const int CH = 2048;
        ln_kernel<float><<<M, 256, 0, stream>>>(out, g2, be2, xn2, D);
        for (int c = 0; c < M / CH; ++c) {
            const size_t roff = (size_t)c * CH;
            gemm_mfma<128, bf16, float, true, false, false><<<dim3(F / 128, CH / 128), 256, 0, stream>>>(
                xn2 + roff * D, w1T, bf1, nullptr, nullptr, (const float*)nullptr, hid, CH, F, D);
            gemm_mfma<64, float, float, false, true, false><<<dim3(D / 128, CH / 64), 256, 0, stream>>>(
                hid, w2T, bf2, nullptr, nullptr, out + roff * D, out + roff * D, CH, D, F);
        }
    }
}

// Round 4
// 398.678 us; speedup vs baseline: 1.0200x; 1.0200x over previous
//
#include <hip/hip_runtime.h>
#include <hip/hip_bf16.h>

// Transformer block: LN1 -> QKV -> MHA(16 heads, hd=64) -> out-proj + resid
//                    -> LN2 -> FFN(4x, ReLU) + resid
// B=2, S=2048, D=1024, H=16, hd=64, F=4096. M = B*S = 4096.
// fp32 buffers in/out; bf16 intermediates (fp32 accumulation).
//
// Round 14: round-13's j-split structure was right (occupancy 19.6->40.8%)
// but __launch_bounds__(512,4) was interpreted as 4 BLOCKS/CU (CUDA
// semantics) -> VGPR capped at 64 (=512/8 waves/SIMD) -> heavy spills:
// WRITE_SIZE 8MB->70MB of scratch, VALUBusy 48->34, net regression.
// Fix: __launch_bounds__(512,2) -> VGPR cap 128 under blocks-semantics
// (256 under waves-semantics); state fits in ~104 (round-12 evidence),
// no spills; LDS (71KB) still caps residency at the intended 2 blocks/CU.
// Structure unchanged: waves 0-3 even j-tiles, 4-7 odd, per-group T14
// double-buffered K/V staging, 2-way online-softmax merge epilogue.
// GEMM pipeline unchanged from round 9 (BK=64 + XOR chunk swizzle).

using bf16 = __hip_bfloat16;
typedef short bf16x8 __attribute__((ext_vector_type(8)));
typedef short bf16x4v __attribute__((ext_vector_type(4)));
typedef float f32x4 __attribute__((ext_vector_type(4)));

#if defined(__has_builtin)
#  if __has_builtin(__builtin_amdgcn_mfma_f32_16x16x16bf16_1k)
#    define HAVE_MFMA_K16 1
#  endif
#  if __has_builtin(__builtin_amdgcn_exp2f)
#    define EXP2F(x) __builtin_amdgcn_exp2f(x)
#  endif
#endif
#ifndef EXP2F
#  define EXP2F(x) __expf(0.6931471805599453f * (x))
#endif

__device__ __forceinline__ float toF(float v) { return v; }
__device__ __forceinline__ float toF(bf16 v) { return __bfloat162float(v); }
__device__ __forceinline__ void storeF(float* p, float v) { *p = v; }
__device__ __forceinline__ void storeF(bf16* p, float v) { *p = __float2bfloat16(v); }

__device__ __forceinline__ float waveReduceSum(float v) {
    #pragma unroll
    for (int o = 32; o > 0; o >>= 1) v += __shfl_down(v, o, 64);
    return v;
}

__device__ __forceinline__ void async16(const bf16* g, bf16* l) {
    __builtin_amdgcn_global_load_lds(
        (const __attribute__((address_space(1))) unsigned int*)g,
        (__attribute__((address_space(3))) unsigned int*)l,
        16, 0, 0);
}

__device__ __forceinline__ unsigned short bf16bits(float x) {
    union { bf16 h; unsigned short u; } e; e.h = __float2bfloat16(x);
    return e.u;
}

// ---------------- fused weight transpose + cast (all 6 weights) ------------
__global__ __launch_bounds__(256) void transpose_all(
        const float* __restrict__ wq, const float* __restrict__ wk,
        const float* __restrict__ wv, const float* __restrict__ wo,
        const float* __restrict__ w1, const float* __restrict__ w2,
        bf16* __restrict__ wqkvT, bf16* __restrict__ woT,
        bf16* __restrict__ w1T, bf16* __restrict__ w2T) {
    __shared__ float t[32][33];
    const int tI = blockIdx.x;
    const float* in; bf16* outT; int R, C, tl;
    if (tI < 4096) {
        const int seg = tI >> 10; tl = tI & 1023; R = 1024; C = 1024;
        in = (seg == 0) ? wq : (seg == 1) ? wk : (seg == 2) ? wv : wo;
        outT = (seg == 3) ? woT : wqkvT + (size_t)seg * 1024 * 1024;
    } else if (tI < 8192) {
        tl = tI - 4096; in = w1; outT = w1T; R = 1024; C = 4096;
    } else {
        tl = tI - 8192; in = w2; outT = w2T; R = 4096; C = 1024;
    }
    const int tc = C >> 5;
    const int c0 = (tl % tc) * 32, r0 = (tl / tc) * 32;
    const int lx = threadIdx.x & 31, ly = threadIdx.x >> 5;
    #pragma unroll
    for (int i = 0; i < 32; i += 8)
        t[ly + i][lx] = in[(size_t)(r0 + ly + i) * C + c0 + lx];
    __syncthreads();
    #pragma unroll
    for (int i = 0; i < 32; i += 8)
        outT[(size_t)(c0 + ly + i) * R + r0 + lx] = __float2bfloat16(t[lx][ly + i]);
}

// ---------------- LayerNorm: InT x -> bf16 out ----------------
template <typename InT>
__global__ __launch_bounds__(256) void ln_kernel(const InT* __restrict__ x,
                                                 const float* __restrict__ g,
                                                 const float* __restrict__ b,
                                                 bf16* __restrict__ out, int D) {
    const int row = blockIdx.x;
    const InT* xr = x + (size_t)row * D;
    float s = 0.f, s2 = 0.f;
    for (int i = threadIdx.x; i < D; i += 256) {
        float v = toF(xr[i]);
        s += v; s2 += v * v;
    }
    __shared__ float ws[4], ws2[4];
    int lane = threadIdx.x & 63, wid = threadIdx.x >> 6;
    s = waveReduceSum(s); s2 = waveReduceSum(s2);
    if (lane == 0) { ws[wid] = s; ws2[wid] = s2; }
    __syncthreads();
    float ts = ws[0] + ws[1] + ws[2] + ws[3];
    float ts2 = ws2[0] + ws2[1] + ws2[2] + ws2[3];
    float mean = ts / D;
    float var = ts2 / D - mean * mean;
    float rstd = rsqrtf(var + 1e-5f);
    bf16* outr = out + (size_t)row * D;
    for (int i = threadIdx.x; i < D; i += 256) {
        float v = (toF(xr[i]) - mean) * rstd * g[i] + b[i];
        outr[i] = __float2bfloat16(v);
    }
}

// ---------------- MFMA GEMM: C = act(A @ BT^T + bias) [+ resid] ------------
// BK=64, XOR-swizzled LDS (chunk c of row r stored at slot c^(r&7)).
template <int BM, typename OutT, typename ResidT, bool RELU, bool HAS_RESID, bool BIAS3>
__global__ __launch_bounds__(256) void gemm_mfma(const bf16* __restrict__ A,
                                                 const bf16* __restrict__ BT,
                                                 const float* __restrict__ bias,
                                                 const float* __restrict__ biasK,
                                                 const float* __restrict__ biasV,
                                                 const ResidT* __restrict__ resid,
                                                 OutT* __restrict__ C,
                                                 int M, int N, int K) {
    constexpr int BK = 64;
    constexpr int MI = BM / 32;
    constexpr int AROWS = BM / 4;
    constexpr int ASEC = AROWS / 8;
    __shared__ bf16 As[BM][BK];      // row stride 128 B
    __shared__ bf16 Bs[128][BK];
    const int tid = threadIdx.x, lane = tid & 63, wid = tid >> 6;
    const int m0 = blockIdx.y * BM, n0 = blockIdx.x * 128;
    const int wm = (BM == 128) ? (wid >> 1) * 64 : (wid & 1) * 32;
    const int wn = (BM == 128) ? (wid & 1) * 64 : (wid >> 1) * 64;

    f32x4 acc[MI][4] = {};

    const int srow = lane >> 3;
    const int scol = ((lane & 7) ^ srow) * 8;
    const bf16* Abase = A + (size_t)(m0 + wid * AROWS + srow) * K + scol;
    const bf16* Bbase = BT + (size_t)(n0 + wid * 32 + srow) * K + scol;

    const int fr = lane & 15;
    const int kg = lane >> 4;

    for (int k0 = 0; k0 < K; k0 += BK) {
        #pragma unroll
        for (int s = 0; s < ASEC; ++s)
            async16(Abase + (size_t)(s * 8) * K + k0, &As[wid * AROWS + s * 8][0]);
        #pragma unroll
        for (int s = 0; s < 4; ++s)
            async16(Bbase + (size_t)(s * 8) * K + k0, &Bs[wid * 32 + s * 8][0]);
        __syncthreads();

        #pragma unroll
        for (int ks = 0; ks < 2; ++ks) {
            const int pc = ((ks * 4 + kg) ^ (fr & 7)) * 16;
            bf16x8 aF[MI], bF[4];
            #pragma unroll
            for (int i = 0; i < MI; ++i)
                aF[i] = *(const bf16x8*)((const char*)&As[0][0]
                         + (size_t)(wm + i * 16 + fr) * 128 + pc);
            #pragma unroll
            for (int j = 0; j < 4; ++j)
                bF[j] = *(const bf16x8*)((const char*)&Bs[0][0]
                         + (size_t)(wn + j * 16 + fr) * 128 + pc);
            #pragma unroll
            for (int i = 0; i < MI; ++i)
                #pragma unroll
                for (int j = 0; j < 4; ++j)
                    acc[i][j] = __builtin_amdgcn_mfma_f32_16x16x32_bf16(
                        aF[i], bF[j], acc[i][j], 0, 0, 0);
        }
        __syncthreads();
    }

    const int col_l = lane & 15, row_l = (lane >> 4) * 4;
    #pragma unroll
    for (int j = 0; j < 4; ++j) {
        const int col = n0 + wn + j * 16 + col_l;
        float bvv;
        if (BIAS3) {
            const float* bp = (col < 1024) ? bias : ((col < 2048) ? biasK : biasV);
            bvv = bp[col & 1023];
        } else {
            bvv = bias[col];
        }
        #pragma unroll
        for (int i = 0; i < MI; ++i) {
            #pragma unroll
            for (int r = 0; r < 4; ++r) {
                const int row = m0 + wm + i * 16 + row_l + r;
                float v = acc[i][j][r] + bvv;
                if (RELU) v = fmaxf(v, 0.f);
                if (HAS_RESID) v += toF(resid[(size_t)row * N + col]);
                storeF(&C[(size_t)row * N + col], v);
            }
        }
    }
}

// ---------------- MFMA flash attention, S^T formulation ---------------------
// TQ=128, 512 threads / 8 waves. Waves 0-3 (group 0) do even j-tiles,
// waves 4-7 (group 1) odd j-tiles; per-group double-buffered K/V staging
// (T14 issue-early/write-late). 2-way online-softmax merge in epilogue.
#if HAVE_MFMA_K16
__global__ __launch_bounds__(512, 2) void attn_mfma(const bf16* __restrict__ qkv,
                                                    const int* __restrict__ mask,
                                                    bf16* __restrict__ outp,
                                                    int B, int S, int LD) {
    const int q0 = blockIdx.x * 128;
    const int h = blockIdx.y, b = blockIdx.z;
    const int Do = 1024;
    const int tid = threadIdx.x, lane = tid & 63, wid = tid >> 6;
    const int g = wid >> 2;          // j-parity group
    const int wl = wid & 3;          // wave-in-group: q-strip
    const int stid = tid & 255;      // staging id within group
    const int n = lane & 15, kg = lane >> 4;

    // LDS: [0,33792) K tiles (4 slots of [64][66] bf16, slot = g*2+buf)
    //      [33792,68608) V^T tiles (4 slots of [64][68] bf16)
    //      [68608,70656) mask bias f32 [4][64]; [70656,70672) sAny int [4]
    // Merge overlay (post-loop): po f32[128][65] @0, pm[128] @33280, pl[128] @33792.
    __shared__ __align__(16) char smem[70672];
    bf16* KsBase = (bf16*)smem;
    bf16* VtBase = (bf16*)(smem + 33792);
    float* MskfP = (float*)(smem + 68608);
    int* sAnyP   = (int*)(smem + 70656);

    // Q B-frags, pre-scaled by (1/sqrt(64))*log2(e); wave owns 32 q-rows.
    const float QSCALE = 0.125f * 1.4426950408889634f;
    bf16x8 qf[2][2];
    #pragma unroll
    for (int u = 0; u < 2; ++u) {
        const bf16* qp = qkv + ((size_t)(b * S + q0 + wl * 32 + u * 16 + n)) * LD + h * 64 + kg * 8;
        union { uint4 uu; bf16x8 v; unsigned short s[8]; } c[2];
        c[0].uu = *(const uint4*)qp;
        c[1].uu = *(const uint4*)(qp + 32);
        #pragma unroll
        for (int t = 0; t < 2; ++t) {
            #pragma unroll
            for (int i = 0; i < 8; ++i) {
                union { float f; unsigned int u2; } d;
                d.u2 = ((unsigned int)c[t].s[i]) << 16;
                c[t].s[i] = bf16bits(d.f * QSCALE);
            }
            qf[u][t] = c[t].v;
        }
    }

    f32x4 acc[2][4] = {};
    float m[2] = {-1e30f, -1e30f}, l[2] = {0.f, 0.f};

    const int sr = stid >> 2, sc = (stid & 3) * 16;
    const int jp = stid & 31, dg = (stid >> 5) * 8;
    const bf16* kbase = qkv + (size_t)(b * S) * LD + 1024 + h * 64;
    const bf16* vbase = qkv + (size_t)(b * S) * LD + 2048 + h * 64;

    // staged-tile registers (T14 issue-early / write-late)
    uint4 ka, kc, vau, vcu;
    int mz = 0;

    // prologue: issue group's tile-0 loads (global j-tile index = g)
    {
        const int j0 = g * 64;
        const bf16* kp = kbase + (size_t)(j0 + sr) * LD + sc;
        ka = *(const uint4*)kp;
        kc = *(const uint4*)(kp + 8);
        const bf16* vp = vbase + (size_t)(j0 + 2 * jp) * LD + dg;
        vau = *(const uint4*)vp;
        vcu = *(const uint4*)(vp + LD);
        if (stid < 64) mz = (mask[b * S + j0 + stid] == 0);
    }

    const int NT = S / 64;           // 32 j-tiles total; 16 per group
    for (int it = 0; it < NT / 2; ++it) {
        const int cur = it & 1;
        const int slot = g * 2 + cur;
        bf16* ksb = KsBase + slot * (64 * 66);
        bf16* vtb = VtBase + slot * (64 * 68);

        // ---- write staged tile into LDS (vmcnt wait lands here) ----
        {
            uint* kd = (uint*)((char*)ksb + sr * 132 + sc * 2);
            kd[0] = ka.x; kd[1] = ka.y; kd[2] = ka.z; kd[3] = ka.w;
            kd[4] = kc.x; kd[5] = kc.y; kd[6] = kc.z; kd[7] = kc.w;

            union { uint4 u4; unsigned short s[8]; } va, vc;
            va.u4 = vau; vc.u4 = vcu;
            #pragma unroll
            for (int i = 0; i < 8; ++i) {
                unsigned int pk = (unsigned int)va.s[i] | ((unsigned int)vc.s[i] << 16);
                *(unsigned int*)((char*)vtb + (size_t)(dg + i) * 136 + jp * 4) = pk;
            }
            if (stid < 64) {
                MskfP[slot * 64 + stid] = mz ? -1e9f : 0.f;
                unsigned long long bl = __ballot(mz);
                if (stid == 0) sAnyP[slot] = (bl != 0ull) ? 1 : 0;
            }
        }
        __syncthreads();

        // ---- issue next tile's global loads; latency hides under compute --
        {
            const int tg2 = 2 * (it + 1) + g;
            if (tg2 < NT) {
                const int j0 = tg2 * 64;
                const bf16* kp = kbase + (size_t)(j0 + sr) * LD + sc;
                ka = *(const uint4*)kp;
                kc = *(const uint4*)(kp + 8);
                const bf16* vp = vbase + (size_t)(j0 + 2 * jp) * LD + dg;
                vau = *(const uint4*)vp;
                vcu = *(const uint4*)(vp + LD);
                if (stid < 64) mz = (mask[b * S + j0 + stid] == 0);
            }
        }

        // ---- S^T = K @ Q^T (log2-scaled); K-frags read once ----
        f32x4 st[2][4] = {};
        #pragma unroll
        for (int ks = 0; ks < 2; ++ks) {
            #pragma unroll
            for (int jt = 0; jt < 4; ++jt) {
                union { uint u[4]; bf16x8 v; } kf;
                const uint* bp = (const uint*)((const char*)ksb
                                 + (size_t)(jt * 16 + n) * 132 + ks * 64 + kg * 16);
                kf.u[0] = bp[0]; kf.u[1] = bp[1]; kf.u[2] = bp[2]; kf.u[3] = bp[3];
                st[0][jt] = __builtin_amdgcn_mfma_f32_16x16x32_bf16(kf.v, qf[0][ks], st[0][jt], 0, 0, 0);
                st[1][jt] = __builtin_amdgcn_mfma_f32_16x16x32_bf16(kf.v, qf[1][ks], st[1][jt], 0, 0, 0);
            }
        }

        // ---- mask bias only when the tile actually has masked positions ---
        if (sAnyP[slot]) {
            #pragma unroll
            for (int u = 0; u < 2; ++u) {
                #pragma unroll
                for (int jt = 0; jt < 4; ++jt) {
                    f32x4 mb = *(const f32x4*)&MskfP[slot * 64 + jt * 16 + kg * 4];
                    #pragma unroll
                    for (int r = 0; r < 4; ++r) st[u][jt][r] += mb[r];
                }
            }
        }

        // ---- online softmax with defer-max (THR=8 in log2 domain) ---------
        float mx0 = st[0][0][0], mx1 = st[1][0][0];
        #pragma unroll
        for (int jt = 0; jt < 4; ++jt) {
            #pragma unroll
            for (int r = 0; r < 4; ++r) {
                mx0 = fmaxf(mx0, st[0][jt][r]);
                mx1 = fmaxf(mx1, st[1][jt][r]);
            }
        }
        mx0 = fmaxf(mx0, __shfl_xor(mx0, 16, 64));
        mx0 = fmaxf(mx0, __shfl_xor(mx0, 32, 64));
        mx1 = fmaxf(mx1, __shfl_xor(mx1, 16, 64));
        mx1 = fmaxf(mx1, __shfl_xor(mx1, 32, 64));

        if (__any((mx0 > m[0] + 8.f) || (mx1 > m[1] + 8.f))) {
            float mxa[2] = {mx0, mx1};
            #pragma unroll
            for (int u = 0; u < 2; ++u) {
                float newm = fmaxf(m[u], mxa[u]);
                float alpha = EXP2F(m[u] - newm);
                m[u] = newm;
                l[u] *= alpha;
                #pragma unroll
                for (int dt = 0; dt < 4; ++dt)
                    #pragma unroll
                    for (int r = 0; r < 4; ++r) acc[u][dt][r] *= alpha;
            }
        }

        bf16x4v pf[2][4];
        #pragma unroll
        for (int u = 0; u < 2; ++u) {
            float ls = 0.f;
            #pragma unroll
            for (int jt = 0; jt < 4; ++jt) {
                union { unsigned short s[4]; bf16x4v v; } pk;
                #pragma unroll
                for (int r = 0; r < 4; ++r) {
                    union { float f; unsigned int u2; } p;
                    p.f = EXP2F(st[u][jt][r] - m[u]);
                    p.u2 &= 0xffff0000u;          // truncate to bf16
                    ls += p.f;                    // sum the truncated value
                    pk.s[r] = (unsigned short)(p.u2 >> 16);
                }
                pf[u][jt] = pk.v;
            }
            ls += __shfl_xor(ls, 16, 64);
            ls += __shfl_xor(ls, 32, 64);
            l[u] += ls;
        }

        // ---- O^T += V^T @ P^T; V-frags read once ----
        #pragma unroll
        for (int jt = 0; jt < 4; ++jt) {
            #pragma unroll
            for (int dt = 0; dt < 4; ++dt) {
                union { uint u[2]; bf16x4v v; } vf;
                const uint* vpp = (const uint*)((const char*)vtb
                                  + (size_t)(dt * 16 + n) * 136 + jt * 32 + kg * 8);
                vf.u[0] = vpp[0]; vf.u[1] = vpp[1];
                acc[0][dt] = __builtin_amdgcn_mfma_f32_16x16x16bf16_1k(vf.v, pf[0][jt], acc[0][dt], 0, 0, 0);
                acc[1][dt] = __builtin_amdgcn_mfma_f32_16x16x16bf16_1k(vf.v, pf[1][jt], acc[1][dt], 0, 0, 0);
            }
        }
    }

    // ---- epilogue: 2-way online-softmax merge across groups ----
    __syncthreads();                       // all K/V reads done; overlay safe
    float* po = (float*)smem;              // [128][65]
    float* pm = (float*)(smem + 33280);    // [128]
    float* pl = (float*)(smem + 33792);    // [128]
    if (g == 1) {
        #pragma unroll
        for (int u = 0; u < 2; ++u) {
            const int ql = wl * 32 + u * 16 + n;
            if (kg == 0) { pm[ql] = m[u]; pl[ql] = l[u]; }
            #pragma unroll
            for (int dt = 0; dt < 4; ++dt)
                #pragma unroll
                for (int r = 0; r < 4; ++r)
                    po[ql * 65 + dt * 16 + kg * 4 + r] = acc[u][dt][r];
        }
    }
    __syncthreads();
    if (g == 0) {
        #pragma unroll
        for (int u = 0; u < 2; ++u) {
            const int ql = wl * 32 + u * 16 + n;
            float m1 = pm[ql], l1 = pl[ql];
            float newm = fmaxf(m[u], m1);
            float a0 = EXP2F(m[u] - newm);
            float a1 = EXP2F(m1 - newm);
            float lt = l[u] * a0 + l1 * a1;
            float inv = (lt > 0.f) ? (1.f / lt) : 0.f;
            bf16* op = outp + ((size_t)(b * S + q0 + wl * 32 + u * 16 + n)) * Do + h * 64;
            #pragma unroll
            for (int dt = 0; dt < 4; ++dt) {
                union { unsigned short s[4]; uint2 u2; } w;
                #pragma unroll
                for (int r = 0; r < 4; ++r) {
                    float o1 = po[ql * 65 + dt * 16 + kg * 4 + r];
                    w.s[r] = bf16bits((acc[u][dt][r] * a0 + o1 * a1) * inv);
                }
                *(uint2*)(op + dt * 16 + kg * 4) = w.u2;
            }
        }
    }
}
#else
// Fallback (round-5 structure, 512 threads): 8 waves each own 16 q-rows;
// threads 0-255 stage the shared K/V tile.
__global__ __launch_bounds__(512) void attn_mfma(const bf16* __restrict__ qkv,
                                                 const int* __restrict__ mask,
                                                 bf16* __restrict__ outp,
                                                 int B, int S, int LD) {
    const int h = blockIdx.y, b = blockIdx.z;
    const int Do = 1024;
    const int tid = threadIdx.x, lane = tid & 63, wid = tid >> 6;
    const int n = lane & 15, kg = lane >> 4;
    const int q0 = blockIdx.x * 128;

    __shared__ bf16 Ks[64][66];
    __shared__ bf16 Vt[64][66];
    __shared__ bf16 Plds[8][16][66];
    __shared__ int  Msk[64];

    bf16x8 qf[2];
    {
        const bf16* qp = qkv + ((size_t)(b * S + q0 + wid * 16 + n)) * LD + h * 64 + kg * 8;
        union { uint4 u; bf16x8 v; } c0, c1;
        c0.u = *(const uint4*)qp;
        c1.u = *(const uint4*)(qp + 32);
        qf[0] = c0.v; qf[1] = c1.v;
    }

    f32x4 acc_o[4] = {};
    float m_r[4] = {-1e30f, -1e30f, -1e30f, -1e30f};
    float l_r[4] = {0.f, 0.f, 0.f, 0.f};

    const int sr = tid >> 2;
    const int sc = (tid & 3) * 16;
    const bf16* kbase = qkv + (size_t)(b * S) * LD + 1024 + h * 64;
    const bf16* vbase = qkv + (size_t)(b * S) * LD + 2048 + h * 64;

    for (int j0 = 0; j0 < S; j0 += 64) {
        __syncthreads();
        if (tid < 256) {
            const bf16* kp = kbase + (size_t)(j0 + sr) * LD + sc;
            uint4 ka = *(const uint4*)kp;
            uint4 kbv = *(const uint4*)(kp + 8);
            uint* kd = (uint*)((char*)&Ks[0][0] + sr * 132 + sc * 2);
            kd[0] = ka.x; kd[1] = ka.y; kd[2] = ka.z; kd[3] = ka.w;
            kd[4] = kbv.x; kd[5] = kbv.y; kd[6] = kbv.z; kd[7] = kbv.w;

            const bf16* vp = vbase + (size_t)(j0 + sr) * LD + sc;
            union { uint4 u[2]; unsigned short s[16]; } vv;
            vv.u[0] = *(const uint4*)vp;
            vv.u[1] = *(const uint4*)(vp + 8);
            #pragma unroll
            for (int i = 0; i < 16; ++i)
                *((unsigned short*)((char*)&Vt[0][0] + (size_t)(sc + i) * 132 + sr * 2)) = vv.s[i];

            if (tid < 64) Msk[tid] = mask[b * S + j0 + tid];
        }
        __syncthreads();

        f32x4 st[4] = {};
        #pragma unroll
        for (int ks = 0; ks < 2; ++ks) {
            #pragma unroll
            for (int jt = 0; jt < 4; ++jt) {
                union { uint u[4]; bf16x8 v; } bf;
                const uint* bp = (const uint*)((const char*)&Ks[0][0]
                                 + (size_t)(jt * 16 + n) * 132 + ks * 64 + kg * 16);
                bf.u[0] = bp[0]; bf.u[1] = bp[1]; bf.u[2] = bp[2]; bf.u[3] = bp[3];
                st[jt] = __builtin_amdgcn_mfma_f32_16x16x32_bf16(qf[ks], bf.v, st[jt], 0, 0, 0);
            }
        }

        int mk[4];
        #pragma unroll
        for (int jt = 0; jt < 4; ++jt) mk[jt] = Msk[jt * 16 + n];

        #pragma unroll
        for (int r = 0; r < 4; ++r) {
            float mx = -1e30f;
            #pragma unroll
            for (int jt = 0; jt < 4; ++jt) {
                float s = st[jt][r] * 0.125f;
                if (mk[jt] == 0) s = -1e9f;
                st[jt][r] = s;
                mx = fmaxf(mx, s);
            }
            #pragma unroll
            for (int o = 1; o < 16; o <<= 1) mx = fmaxf(mx, __shfl_xor(mx, o, 64));
            float newm = fmaxf(m_r[r], mx);
            float alpha = __expf(m_r[r] - newm);
            m_r[r] = newm;
            float ls = 0.f;
            #pragma unroll
            for (int jt = 0; jt < 4; ++jt) {
                float p = __expf(st[jt][r] - newm);
                ls += p;
                Plds[wid][kg * 4 + r][jt * 16 + n] = __float2bfloat16(p);
            }
            #pragma unroll
            for (int o = 1; o < 16; o <<= 1) ls += __shfl_xor(ls, o, 64);
            l_r[r] = l_r[r] * alpha + ls;
            #pragma unroll
            for (int dt = 0; dt < 4; ++dt) acc_o[dt][r] *= alpha;
        }

        __asm__ volatile("s_waitcnt lgkmcnt(0)" ::: "memory");

        #pragma unroll
        for (int ks = 0; ks < 2; ++ks) {
            union { uint u[4]; bf16x8 v; } af;
            const uint* ap = (const uint*)((const char*)&Plds[wid][0][0]
                             + (size_t)n * 132 + ks * 64 + kg * 16);
            af.u[0] = ap[0]; af.u[1] = ap[1]; af.u[2] = ap[2]; af.u[3] = ap[3];
            #pragma unroll
            for (int dt = 0; dt < 4; ++dt) {
                union { uint u[4]; bf16x8 v; } bf;
                const uint* bp = (const uint*)((const char*)&Vt[0][0]
                                 + (size_t)(dt * 16 + n) * 132 + ks * 64 + kg * 16);
                bf.u[0] = bp[0]; bf.u[1] = bp[1]; bf.u[2] = bp[2]; bf.u[3] = bp[3];
                acc_o[dt] = __builtin_amdgcn_mfma_f32_16x16x32_bf16(af.v, bf.v, acc_o[dt], 0, 0, 0);
            }
        }
    }

    #pragma unroll
    for (int r = 0; r < 4; ++r) {
        float inv = (l_r[r] > 0.f) ? (1.f / l_r[r]) : 0.f;
        bf16* op = outp + ((size_t)(b * S + q0 + wid * 16 + kg * 4 + r)) * Do + h * 64 + n;
        #pragma unroll
        for (int dt = 0; dt < 4; ++dt)
            op[dt * 16] = __float2bfloat16(acc_o[dt][r] * inv);
    }
}
#endif

extern "C" void kernel_launch(void* const* d_in, const int* in_sizes, int n_in,
                              void* d_out, int out_size, void* d_ws, size_t ws_size,
                              hipStream_t stream) {
    const int B = 2, S = 2048, D = 1024, H = 16, F = 4096;
    const int M = B * S;  // 4096

    const float* x   = (const float*)d_in[0];
    const int*   mask= (const int*)  d_in[1];
    const float* wq  = (const float*)d_in[2];
    const float* bq  = (const float*)d_in[3];
    const float* wk  = (const float*)d_in[4];
    const float* bk  = (const float*)d_in[5];
    const float* wv  = (const float*)d_in[6];
    const float* bv  = (const float*)d_in[7];
    const float* wo  = (const float*)d_in[8];
    const float* bo  = (const float*)d_in[9];
    const float* g1  = (const float*)d_in[10];
    const float* be1 = (const float*)d_in[11];
    const float* g2  = (const float*)d_in[12];
    const float* be2 = (const float*)d_in[13];
    const float* w1  = (const float*)d_in[14];
    const float* bf1 = (const float*)d_in[15];
    const float* w2  = (const float*)d_in[16];
    const float* bf2 = (const float*)d_in[17];
    float* out = (float*)d_out;

    char* ws = (char*)d_ws;
    const size_t MB = 1024 * 1024;
    bf16* wqkvT = (bf16*)(ws + 0 * MB);            // [3072,1024]
    bf16* woT   = (bf16*)(ws + 6 * MB);
    bf16* w1T   = (bf16*)(ws + 8 * MB);
    bf16* w2T   = (bf16*)(ws + 16 * MB);
    bf16* xn    = (bf16*)(ws + 24 * MB);
    bf16* qkv   = (bf16*)(ws + 32 * MB);           // [4096,3072]
    bf16* att   = xn;                              // reuse
    // x2 (fp32 residual carrier) lives in d_out.

    const bool fullM = (ws_size >= 64 * MB);

    transpose_all<<<12288, 256, 0, stream>>>(wq, wk, wv, wo, w1, w2,
                                             wqkvT, woT, w1T, w2T);

    ln_kernel<float><<<M, 256, 0, stream>>>(x, g1, be1, xn, D);

    gemm_mfma<128, bf16, float, false, false, true><<<dim3(3072 / 128, M / 128), 256, 0, stream>>>(
        xn, wqkvT, bq, bk, bv, (const float*)nullptr, qkv, M, 3072, D);

    attn_mfma<<<dim3(S / 128, H, B), 512, 0, stream>>>(qkv, mask, att, B, S, 3072);

    gemm_mfma<64, float, float, false, true, false><<<dim3(D / 128, M / 64), 256, 0, stream>>>(
        att, woT, bo, nullptr, nullptr, x, out, M, D, D);

    if (fullM) {
        bf16* hid = (bf16*)(ws + 24 * MB);   // [4096,4096] at [24,56)
        bf16* xn2 = (bf16*)(ws + 56 * MB);   // [4096,1024] at [56,64)
        ln_kernel<float><<<M, 256, 0, stream>>>(out, g2, be2, xn2, D);
        gemm_mfma<128, bf16, float, true, false, false><<<dim3(F / 128, M / 128), 256, 0, stream>>>(
            xn2, w1T, bf1, nullptr, nullptr, (const float*)nullptr, hid, M, F, D);
        gemm_mfma<64, float, float, false, true, false><<<dim3(D / 128, M / 64), 256, 0, stream>>>(
            hid, w2T, bf2, nullptr, nullptr, out, out, M, D, F);
    } else {
        bf16* xn2 = (bf16*)(ws + 32 * MB);   // q-section reuse
        bf16* hid = (bf16*)(ws + 40 * MB);   // k+v sections, [2048,4096]
        const int CH = 2048;
        ln_kernel<float><<<M, 256, 0, stream>>>(out, g2, be2, xn2, D);
        for (int c = 0; c < M / CH; ++c) {
            const size_t roff = (size_t)c * CH;
            gemm_mfma<128, bf16, float, true, false, false><<<dim3(F / 128, CH / 128), 256, 0, stream>>>(
                xn2 + roff * D, w1T, bf1, nullptr, nullptr, (const float*)nullptr, hid, CH, F, D);
            gemm_mfma<64, float, float, false, true, false><<<dim3(D / 128, CH / 64), 256, 0, stream>>>(
                hid, w2T, bf2, nullptr, nullptr, out + roff * D, out + roff * D, CH, D, F);
        }
    }
}

// Round 5
// 387.505 us; speedup vs baseline: 1.0494x; 1.0288x over previous
//
#include <hip/hip_runtime.h>
#include <hip/hip_bf16.h>

// Transformer block: LN1 -> QKV -> MHA(16 heads, hd=64) -> out-proj + resid
//                    -> LN2 -> FFN(4x, ReLU) + resid
// B=2, S=2048, D=1024, H=16, hd=64, F=4096. M = B*S = 4096.
// fp32 buffers in/out; bf16 intermediates (fp32 accumulation).
//
// Round 15: attn occupancy arc (rounds 11/13/14) all failed to beat the
// round-12 kernel (86us) - launch_bounds(512,N) on this stack pins ~N/2
// blocks/CU and caps VGPR, so the j-split never got its 2 blocks/CU.
// Revert attn to round-12 exactly. The real remaining bucket is the GEMMs
// (~265us at ~400-500 TF, m97-style 2-barrier structure). This round's
// experiment: FFN1 (4096x4096x1024) moves to the 256^2 8-phase schedule
// (T2 swizzle + T3/T4 counted-vmcnt phases + T5 setprio): 512 thr / 8
// waves (2Mx4N, 128x64/wave), dbuf 128KB LDS, 4 phases per K-tile
// {ds_read subtile; front-loaded stage of tile t+1; raw s_barrier;
// setprio(1); 16 MFMA; setprio(0)}, vmcnt(0) only at phase 3 (issued >=2
// phases earlier - no full drain at barriers). Staging/read swizzle math
// copied verbatim from the proven 128^2 kernel.

using bf16 = __hip_bfloat16;
typedef short bf16x8 __attribute__((ext_vector_type(8)));
typedef short bf16x4v __attribute__((ext_vector_type(4)));
typedef float f32x4 __attribute__((ext_vector_type(4)));

#if defined(__has_builtin)
#  if __has_builtin(__builtin_amdgcn_mfma_f32_16x16x16bf16_1k)
#    define HAVE_MFMA_K16 1
#  endif
#  if __has_builtin(__builtin_amdgcn_exp2f)
#    define EXP2F(x) __builtin_amdgcn_exp2f(x)
#  endif
#  if __has_builtin(__builtin_amdgcn_sched_barrier)
#    define SCHED_BARRIER() __builtin_amdgcn_sched_barrier(0)
#  endif
#  if __has_builtin(__builtin_amdgcn_s_setprio)
#    define SETPRIO(x) __builtin_amdgcn_s_setprio(x)
#  endif
#endif
#ifndef EXP2F
#  define EXP2F(x) __expf(0.6931471805599453f * (x))
#endif
#ifndef SCHED_BARRIER
#  define SCHED_BARRIER()
#endif
#ifndef SETPRIO
#  define SETPRIO(x)
#endif

__device__ __forceinline__ float toF(float v) { return v; }
__device__ __forceinline__ float toF(bf16 v) { return __bfloat162float(v); }
__device__ __forceinline__ void storeF(float* p, float v) { *p = v; }
__device__ __forceinline__ void storeF(bf16* p, float v) { *p = __float2bfloat16(v); }

__device__ __forceinline__ float waveReduceSum(float v) {
    #pragma unroll
    for (int o = 32; o > 0; o >>= 1) v += __shfl_down(v, o, 64);
    return v;
}

__device__ __forceinline__ void async16(const bf16* g, bf16* l) {
    __builtin_amdgcn_global_load_lds(
        (const __attribute__((address_space(1))) unsigned int*)g,
        (__attribute__((address_space(3))) unsigned int*)l,
        16, 0, 0);
}

__device__ __forceinline__ unsigned short bf16bits(float x) {
    union { bf16 h; unsigned short u; } e; e.h = __float2bfloat16(x);
    return e.u;
}

// ---------------- fused weight transpose + cast (all 6 weights) ------------
__global__ __launch_bounds__(256) void transpose_all(
        const float* __restrict__ wq, const float* __restrict__ wk,
        const float* __restrict__ wv, const float* __restrict__ wo,
        const float* __restrict__ w1, const float* __restrict__ w2,
        bf16* __restrict__ wqkvT, bf16* __restrict__ woT,
        bf16* __restrict__ w1T, bf16* __restrict__ w2T) {
    __shared__ float t[32][33];
    const int tI = blockIdx.x;
    const float* in; bf16* outT; int R, C, tl;
    if (tI < 4096) {
        const int seg = tI >> 10; tl = tI & 1023; R = 1024; C = 1024;
        in = (seg == 0) ? wq : (seg == 1) ? wk : (seg == 2) ? wv : wo;
        outT = (seg == 3) ? woT : wqkvT + (size_t)seg * 1024 * 1024;
    } else if (tI < 8192) {
        tl = tI - 4096; in = w1; outT = w1T; R = 1024; C = 4096;
    } else {
        tl = tI - 8192; in = w2; outT = w2T; R = 4096; C = 1024;
    }
    const int tc = C >> 5;
    const int c0 = (tl % tc) * 32, r0 = (tl / tc) * 32;
    const int lx = threadIdx.x & 31, ly = threadIdx.x >> 5;
    #pragma unroll
    for (int i = 0; i < 32; i += 8)
        t[ly + i][lx] = in[(size_t)(r0 + ly + i) * C + c0 + lx];
    __syncthreads();
    #pragma unroll
    for (int i = 0; i < 32; i += 8)
        outT[(size_t)(c0 + ly + i) * R + r0 + lx] = __float2bfloat16(t[lx][ly + i]);
}

// ---------------- LayerNorm: InT x -> bf16 out ----------------
template <typename InT>
__global__ __launch_bounds__(256) void ln_kernel(const InT* __restrict__ x,
                                                 const float* __restrict__ g,
                                                 const float* __restrict__ b,
                                                 bf16* __restrict__ out, int D) {
    const int row = blockIdx.x;
    const InT* xr = x + (size_t)row * D;
    float s = 0.f, s2 = 0.f;
    for (int i = threadIdx.x; i < D; i += 256) {
        float v = toF(xr[i]);
        s += v; s2 += v * v;
    }
    __shared__ float ws[4], ws2[4];
    int lane = threadIdx.x & 63, wid = threadIdx.x >> 6;
    s = waveReduceSum(s); s2 = waveReduceSum(s2);
    if (lane == 0) { ws[wid] = s; ws2[wid] = s2; }
    __syncthreads();
    float ts = ws[0] + ws[1] + ws[2] + ws[3];
    float ts2 = ws2[0] + ws2[1] + ws2[2] + ws2[3];
    float mean = ts / D;
    float var = ts2 / D - mean * mean;
    float rstd = rsqrtf(var + 1e-5f);
    bf16* outr = out + (size_t)row * D;
    for (int i = threadIdx.x; i < D; i += 256) {
        float v = (toF(xr[i]) - mean) * rstd * g[i] + b[i];
        outr[i] = __float2bfloat16(v);
    }
}

// ---------------- MFMA GEMM: C = act(A @ BT^T + bias) [+ resid] ------------
// BK=64, XOR-swizzled LDS (chunk c of row r stored at slot c^(r&7)).
template <int BM, typename OutT, typename ResidT, bool RELU, bool HAS_RESID, bool BIAS3>
__global__ __launch_bounds__(256) void gemm_mfma(const bf16* __restrict__ A,
                                                 const bf16* __restrict__ BT,
                                                 const float* __restrict__ bias,
                                                 const float* __restrict__ biasK,
                                                 const float* __restrict__ biasV,
                                                 const ResidT* __restrict__ resid,
                                                 OutT* __restrict__ C,
                                                 int M, int N, int K) {
    constexpr int BK = 64;
    constexpr int MI = BM / 32;
    constexpr int AROWS = BM / 4;
    constexpr int ASEC = AROWS / 8;
    __shared__ bf16 As[BM][BK];      // row stride 128 B
    __shared__ bf16 Bs[128][BK];
    const int tid = threadIdx.x, lane = tid & 63, wid = tid >> 6;
    const int m0 = blockIdx.y * BM, n0 = blockIdx.x * 128;
    const int wm = (BM == 128) ? (wid >> 1) * 64 : (wid & 1) * 32;
    const int wn = (BM == 128) ? (wid & 1) * 64 : (wid >> 1) * 64;

    f32x4 acc[MI][4] = {};

    const int srow = lane >> 3;
    const int scol = ((lane & 7) ^ srow) * 8;
    const bf16* Abase = A + (size_t)(m0 + wid * AROWS + srow) * K + scol;
    const bf16* Bbase = BT + (size_t)(n0 + wid * 32 + srow) * K + scol;

    const int fr = lane & 15;
    const int kg = lane >> 4;

    for (int k0 = 0; k0 < K; k0 += BK) {
        #pragma unroll
        for (int s = 0; s < ASEC; ++s)
            async16(Abase + (size_t)(s * 8) * K + k0, &As[wid * AROWS + s * 8][0]);
        #pragma unroll
        for (int s = 0; s < 4; ++s)
            async16(Bbase + (size_t)(s * 8) * K + k0, &Bs[wid * 32 + s * 8][0]);
        __syncthreads();

        #pragma unroll
        for (int ks = 0; ks < 2; ++ks) {
            const int pc = ((ks * 4 + kg) ^ (fr & 7)) * 16;
            bf16x8 aF[MI], bF[4];
            #pragma unroll
            for (int i = 0; i < MI; ++i)
                aF[i] = *(const bf16x8*)((const char*)&As[0][0]
                         + (size_t)(wm + i * 16 + fr) * 128 + pc);
            #pragma unroll
            for (int j = 0; j < 4; ++j)
                bF[j] = *(const bf16x8*)((const char*)&Bs[0][0]
                         + (size_t)(wn + j * 16 + fr) * 128 + pc);
            #pragma unroll
            for (int i = 0; i < MI; ++i)
                #pragma unroll
                for (int j = 0; j < 4; ++j)
                    acc[i][j] = __builtin_amdgcn_mfma_f32_16x16x32_bf16(
                        aF[i], bF[j], acc[i][j], 0, 0, 0);
        }
        __syncthreads();
    }

    const int col_l = lane & 15, row_l = (lane >> 4) * 4;
    #pragma unroll
    for (int j = 0; j < 4; ++j) {
        const int col = n0 + wn + j * 16 + col_l;
        float bvv;
        if (BIAS3) {
            const float* bp = (col < 1024) ? bias : ((col < 2048) ? biasK : biasV);
            bvv = bp[col & 1023];
        } else {
            bvv = bias[col];
        }
        #pragma unroll
        for (int i = 0; i < MI; ++i) {
            #pragma unroll
            for (int r = 0; r < 4; ++r) {
                const int row = m0 + wm + i * 16 + row_l + r;
                float v = acc[i][j][r] + bvv;
                if (RELU) v = fmaxf(v, 0.f);
                if (HAS_RESID) v += toF(resid[(size_t)row * N + col]);
                storeF(&C[(size_t)row * N + col], v);
            }
        }
    }
}

// ---------------- 256x256 8-phase MFMA GEMM (T2+T3+T4+T5) ------------------
// 512 threads / 8 waves (2M x 4N); per-wave output 128x64; BK=64.
// Double-buffered 128KB LDS; 4 phases per K-tile; counted vmcnt (drain only
// at phase 3, for stages issued >=2 phases earlier); raw s_barrier (no
// implicit vmcnt/lgkmcnt drain); setprio around each 16-MFMA cluster.
template <bool RELU>
__global__ __launch_bounds__(512, 1) void gemm_mfma256(const bf16* __restrict__ A,
                                                       const bf16* __restrict__ BT,
                                                       const float* __restrict__ bias,
                                                       bf16* __restrict__ C,
                                                       int M, int N, int K) {
    constexpr int BK = 64;
    __shared__ bf16 As[2][256][BK];
    __shared__ bf16 Bs[2][256][BK];
    const int tid = threadIdx.x, lane = tid & 63, wid = tid >> 6;
    const int m0 = blockIdx.y * 256, n0 = blockIdx.x * 256;
    const int wm = (wid >> 2) * 128, wn = (wid & 3) * 64;

    f32x4 acc[8][4] = {};

    const int srow = lane >> 3;
    const int scol = ((lane & 7) ^ srow) * 8;   // pre-swizzled source chunk
    const bf16* Abase = A + (size_t)(m0 + wid * 16 + srow) * K + scol;
    const bf16* Bbase = BT + (size_t)(n0 + wid * 16 + srow) * K + scol;

    const int fr = lane & 15;
    const int kg = lane >> 4;
    const int NT = K / BK;

    // prologue: stage tile 0 into buf 0 (A: 4 calls/wave, B: 4 calls/wave)
    #pragma unroll
    for (int h = 0; h < 2; ++h)
        #pragma unroll
        for (int s = 0; s < 2; ++s) {
            async16(Abase + (size_t)(h * 128 + s * 8) * K,
                    &As[0][h * 128 + wid * 16 + s * 8][0]);
            async16(Bbase + (size_t)(h * 128 + s * 8) * K,
                    &Bs[0][h * 128 + wid * 16 + s * 8][0]);
        }
    asm volatile("s_waitcnt vmcnt(0)" ::: "memory");
    __builtin_amdgcn_s_barrier();
    SCHED_BARRIER();

    for (int t = 0; t < NT; ++t) {
        const int cur = t & 1;
        const size_t k1 = (size_t)(t + 1) * BK;
        const char* ab = (const char*)&As[cur][0][0];
        const char* bb = (const char*)&Bs[cur][0][0];
        const bool pf = (t + 1 < NT);
        bf16x8 aF[4][2], bF[4][2];

        // ---- phase 0: read A rows0-3 + B cols0-1; stage next A ----
        #pragma unroll
        for (int i = 0; i < 4; ++i)
            #pragma unroll
            for (int kk = 0; kk < 2; ++kk)
                aF[i][kk] = *(const bf16x8*)(ab + (size_t)(wm + i * 16 + fr) * 128
                                             + ((kk * 4 + kg) ^ (fr & 7)) * 16);
        #pragma unroll
        for (int j = 0; j < 2; ++j)
            #pragma unroll
            for (int kk = 0; kk < 2; ++kk)
                bF[j][kk] = *(const bf16x8*)(bb + (size_t)(wn + j * 16 + fr) * 128
                                             + ((kk * 4 + kg) ^ (fr & 7)) * 16);
        if (pf) {
            #pragma unroll
            for (int h = 0; h < 2; ++h)
                #pragma unroll
                for (int s = 0; s < 2; ++s)
                    async16(Abase + (size_t)(h * 128 + s * 8) * K + k1,
                            &As[cur ^ 1][h * 128 + wid * 16 + s * 8][0]);
        }
        __builtin_amdgcn_s_barrier();
        SCHED_BARRIER();
        SETPRIO(1);
        #pragma unroll
        for (int i = 0; i < 4; ++i)
            #pragma unroll
            for (int j = 0; j < 2; ++j)
                #pragma unroll
                for (int kk = 0; kk < 2; ++kk)
                    acc[i][j] = __builtin_amdgcn_mfma_f32_16x16x32_bf16(
                        aF[i][kk], bF[j][kk], acc[i][j], 0, 0, 0);
        SETPRIO(0);

        // ---- phase 1: read B cols2-3; stage next B ----
        #pragma unroll
        for (int j = 2; j < 4; ++j)
            #pragma unroll
            for (int kk = 0; kk < 2; ++kk)
                bF[j][kk] = *(const bf16x8*)(bb + (size_t)(wn + j * 16 + fr) * 128
                                             + ((kk * 4 + kg) ^ (fr & 7)) * 16);
        if (pf) {
            #pragma unroll
            for (int h = 0; h < 2; ++h)
                #pragma unroll
                for (int s = 0; s < 2; ++s)
                    async16(Bbase + (size_t)(h * 128 + s * 8) * K + k1,
                            &Bs[cur ^ 1][h * 128 + wid * 16 + s * 8][0]);
        }
        __builtin_amdgcn_s_barrier();
        SCHED_BARRIER();
        SETPRIO(1);
        #pragma unroll
        for (int i = 0; i < 4; ++i)
            #pragma unroll
            for (int j = 2; j < 4; ++j)
                #pragma unroll
                for (int kk = 0; kk < 2; ++kk)
                    acc[i][j] = __builtin_amdgcn_mfma_f32_16x16x32_bf16(
                        aF[i][kk], bF[j][kk], acc[i][j], 0, 0, 0);
        SETPRIO(0);

        // ---- phase 2: read A rows4-7 (reuse aF regs) ----
        #pragma unroll
        for (int i = 0; i < 4; ++i)
            #pragma unroll
            for (int kk = 0; kk < 2; ++kk)
                aF[i][kk] = *(const bf16x8*)(ab + (size_t)(wm + (i + 4) * 16 + fr) * 128
                                             + ((kk * 4 + kg) ^ (fr & 7)) * 16);
        __builtin_amdgcn_s_barrier();
        SCHED_BARRIER();
        SETPRIO(1);
        #pragma unroll
        for (int i = 0; i < 4; ++i)
            #pragma unroll
            for (int j = 0; j < 2; ++j)
                #pragma unroll
                for (int kk = 0; kk < 2; ++kk)
                    acc[i + 4][j] = __builtin_amdgcn_mfma_f32_16x16x32_bf16(
                        aF[i][kk], bF[j][kk], acc[i + 4][j], 0, 0, 0);
        SETPRIO(0);

        // ---- phase 3: publish next tile (vmcnt for stages issued in ph0/1) -
        if (pf) asm volatile("s_waitcnt vmcnt(0)" ::: "memory");
        __builtin_amdgcn_s_barrier();
        SCHED_BARRIER();
        SETPRIO(1);
        #pragma unroll
        for (int i = 0; i < 4; ++i)
            #pragma unroll
            for (int j = 2; j < 4; ++j)
                #pragma unroll
                for (int kk = 0; kk < 2; ++kk)
                    acc[i + 4][j] = __builtin_amdgcn_mfma_f32_16x16x32_bf16(
                        aF[i][kk], bF[j][kk], acc[i + 4][j], 0, 0, 0);
        SETPRIO(0);
    }

    // ---- epilogue: bias (+ReLU), bf16 store ----
    const int col_l = lane & 15, row_l = (lane >> 4) * 4;
    #pragma unroll
    for (int j = 0; j < 4; ++j) {
        const int col = n0 + wn + j * 16 + col_l;
        const float bvv = bias[col];
        #pragma unroll
        for (int i = 0; i < 8; ++i) {
            #pragma unroll
            for (int r = 0; r < 4; ++r) {
                const int row = m0 + wm + i * 16 + row_l + r;
                float v = acc[i][j][r] + bvv;
                if (RELU) v = fmaxf(v, 0.f);
                C[(size_t)row * N + col] = __float2bfloat16(v);
            }
        }
    }
}

// ---------------- MFMA flash attention, S^T formulation, TQ=128 ------------
// Round-12 version (best measured: 86us). Double-buffered K/V staging (T14):
// write tile t -> LDS buf[t&1], one barrier, issue tile t+1 global loads to
// regs, compute. Mask-skip + defer-max (THR=8, log2 domain).
#if HAVE_MFMA_K16
__global__ __launch_bounds__(256) void attn_mfma(const bf16* __restrict__ qkv,
                                                 const int* __restrict__ mask,
                                                 bf16* __restrict__ outp,
                                                 int B, int S, int LD) {
    const int q0 = blockIdx.x * 128;
    const int h = blockIdx.y, b = blockIdx.z;
    const int Do = 1024;
    const int tid = threadIdx.x, lane = tid & 63, wid = tid >> 6;
    const int n = lane & 15, kg = lane >> 4;

    __shared__ bf16 Ks[2][64][66];   // K tile [j][d], 132B rows
    __shared__ bf16 Vt[2][64][68];   // V^T tile [d][j], 136B rows
    __shared__ float Mskf[2][64];    // additive mask bias (log2 domain)
    __shared__ int sAny[2];          // any masked position in this j-tile?

    // Q B-frags, pre-scaled by (1/sqrt(64))*log2(e); wave owns 32 q-rows.
    const float QSCALE = 0.125f * 1.4426950408889634f;
    bf16x8 qf[2][2];
    #pragma unroll
    for (int u = 0; u < 2; ++u) {
        const bf16* qp = qkv + ((size_t)(b * S + q0 + wid * 32 + u * 16 + n)) * LD + h * 64 + kg * 8;
        union { uint4 uu; bf16x8 v; unsigned short s[8]; } c[2];
        c[0].uu = *(const uint4*)qp;
        c[1].uu = *(const uint4*)(qp + 32);
        #pragma unroll
        for (int t = 0; t < 2; ++t) {
            #pragma unroll
            for (int i = 0; i < 8; ++i) {
                union { float f; unsigned int u2; } d;
                d.u2 = ((unsigned int)c[t].s[i]) << 16;
                c[t].s[i] = bf16bits(d.f * QSCALE);
            }
            qf[u][t] = c[t].v;
        }
    }

    f32x4 acc[2][4] = {};
    float m[2] = {-1e30f, -1e30f}, l[2] = {0.f, 0.f};

    const int sr = tid >> 2, sc = (tid & 3) * 16;
    const int jp = tid & 31, dg = (tid >> 5) * 8;
    const bf16* kbase = qkv + (size_t)(b * S) * LD + 1024 + h * 64;
    const bf16* vbase = qkv + (size_t)(b * S) * LD + 2048 + h * 64;

    // staged-tile registers (T14 issue-early / write-late)
    uint4 ka, kc, vau, vcu;
    int mz = 0;

    // prologue: issue tile-0 loads
    {
        const bf16* kp = kbase + (size_t)sr * LD + sc;
        ka = *(const uint4*)kp;
        kc = *(const uint4*)(kp + 8);
        const bf16* vp = vbase + (size_t)(2 * jp) * LD + dg;
        vau = *(const uint4*)vp;
        vcu = *(const uint4*)(vp + LD);
        if (tid < 64) mz = (mask[b * S + tid] == 0);
    }

    const int NT = S / 64;
    for (int t = 0; t < NT; ++t) {
        const int cur = t & 1;

        // ---- write staged tile t into LDS buf[cur] (vmcnt wait lands here) -
        {
            uint* kd = (uint*)((char*)&Ks[cur][0][0] + sr * 132 + sc * 2);
            kd[0] = ka.x; kd[1] = ka.y; kd[2] = ka.z; kd[3] = ka.w;
            kd[4] = kc.x; kd[5] = kc.y; kd[6] = kc.z; kd[7] = kc.w;

            union { uint4 u4; unsigned short s[8]; } va, vc;
            va.u4 = vau; vc.u4 = vcu;
            #pragma unroll
            for (int i = 0; i < 8; ++i) {
                unsigned int pk = (unsigned int)va.s[i] | ((unsigned int)vc.s[i] << 16);
                *(unsigned int*)((char*)&Vt[cur][0][0] + (size_t)(dg + i) * 136 + jp * 4) = pk;
            }
            if (tid < 64) {
                Mskf[cur][tid] = mz ? -1e9f : 0.f;
                unsigned long long bl = __ballot(mz);
                if (tid == 0) sAny[cur] = (bl != 0ull) ? 1 : 0;
            }
        }
        __syncthreads();

        // ---- issue tile t+1 global loads; latency hides under compute -----
        if (t + 1 < NT) {
            const int j0 = (t + 1) * 64;
            const bf16* kp = kbase + (size_t)(j0 + sr) * LD + sc;
            ka = *(const uint4*)kp;
            kc = *(const uint4*)(kp + 8);
            const bf16* vp = vbase + (size_t)(j0 + 2 * jp) * LD + dg;
            vau = *(const uint4*)vp;
            vcu = *(const uint4*)(vp + LD);
            if (tid < 64) mz = (mask[b * S + j0 + tid] == 0);
        }

        // ---- S^T = K @ Q^T (log2-scaled); K-frags read once ----
        f32x4 st[2][4] = {};
        #pragma unroll
        for (int ks = 0; ks < 2; ++ks) {
            #pragma unroll
            for (int jt = 0; jt < 4; ++jt) {
                union { uint u[4]; bf16x8 v; } kf;
                const uint* bp = (const uint*)((const char*)&Ks[cur][0][0]
                                 + (size_t)(jt * 16 + n) * 132 + ks * 64 + kg * 16);
                kf.u[0] = bp[0]; kf.u[1] = bp[1]; kf.u[2] = bp[2]; kf.u[3] = bp[3];
                st[0][jt] = __builtin_amdgcn_mfma_f32_16x16x32_bf16(kf.v, qf[0][ks], st[0][jt], 0, 0, 0);
                st[1][jt] = __builtin_amdgcn_mfma_f32_16x16x32_bf16(kf.v, qf[1][ks], st[1][jt], 0, 0, 0);
            }
        }

        // ---- mask bias only when the tile actually has masked positions ---
        if (sAny[cur]) {
            #pragma unroll
            for (int u = 0; u < 2; ++u) {
                #pragma unroll
                for (int jt = 0; jt < 4; ++jt) {
                    f32x4 mb = *(const f32x4*)&Mskf[cur][jt * 16 + kg * 4];
                    #pragma unroll
                    for (int r = 0; r < 4; ++r) st[u][jt][r] += mb[r];
                }
            }
        }

        // ---- online softmax with defer-max (THR=8 in log2 domain) ---------
        float mx0 = st[0][0][0], mx1 = st[1][0][0];
        #pragma unroll
        for (int jt = 0; jt < 4; ++jt) {
            #pragma unroll
            for (int r = 0; r < 4; ++r) {
                mx0 = fmaxf(mx0, st[0][jt][r]);
                mx1 = fmaxf(mx1, st[1][jt][r]);
            }
        }
        mx0 = fmaxf(mx0, __shfl_xor(mx0, 16, 64));
        mx0 = fmaxf(mx0, __shfl_xor(mx0, 32, 64));
        mx1 = fmaxf(mx1, __shfl_xor(mx1, 16, 64));
        mx1 = fmaxf(mx1, __shfl_xor(mx1, 32, 64));

        if (__any((mx0 > m[0] + 8.f) || (mx1 > m[1] + 8.f))) {
            float mxa[2] = {mx0, mx1};
            #pragma unroll
            for (int u = 0; u < 2; ++u) {
                float newm = fmaxf(m[u], mxa[u]);
                float alpha = EXP2F(m[u] - newm);
                m[u] = newm;
                l[u] *= alpha;
                #pragma unroll
                for (int dt = 0; dt < 4; ++dt)
                    #pragma unroll
                    for (int r = 0; r < 4; ++r) acc[u][dt][r] *= alpha;
            }
        }

        bf16x4v pf[2][4];
        #pragma unroll
        for (int u = 0; u < 2; ++u) {
            float ls = 0.f;
            #pragma unroll
            for (int jt = 0; jt < 4; ++jt) {
                union { unsigned short s[4]; bf16x4v v; } pk;
                #pragma unroll
                for (int r = 0; r < 4; ++r) {
                    union { float f; unsigned int u2; } p;
                    p.f = EXP2F(st[u][jt][r] - m[u]);
                    p.u2 &= 0xffff0000u;          // truncate to bf16
                    ls += p.f;                    // sum the truncated value
                    pk.s[r] = (unsigned short)(p.u2 >> 16);
                }
                pf[u][jt] = pk.v;
            }
            ls += __shfl_xor(ls, 16, 64);
            ls += __shfl_xor(ls, 32, 64);
            l[u] += ls;
        }

        // ---- O^T += V^T @ P^T; V-frags read once ----
        #pragma unroll
        for (int jt = 0; jt < 4; ++jt) {
            #pragma unroll
            for (int dt = 0; dt < 4; ++dt) {
                union { uint u[2]; bf16x4v v; } vf;
                const uint* vpp = (const uint*)((const char*)&Vt[cur][0][0]
                                  + (size_t)(dt * 16 + n) * 136 + jt * 32 + kg * 8);
                vf.u[0] = vpp[0]; vf.u[1] = vpp[1];
                acc[0][dt] = __builtin_amdgcn_mfma_f32_16x16x16bf16_1k(vf.v, pf[0][jt], acc[0][dt], 0, 0, 0);
                acc[1][dt] = __builtin_amdgcn_mfma_f32_16x16x16bf16_1k(vf.v, pf[1][jt], acc[1][dt], 0, 0, 0);
            }
        }
    }

    // ---- epilogue ----
    #pragma unroll
    for (int u = 0; u < 2; ++u) {
        float inv = (l[u] > 0.f) ? (1.f / l[u]) : 0.f;
        bf16* op = outp + ((size_t)(b * S + q0 + wid * 32 + u * 16 + n)) * Do + h * 64;
        #pragma unroll
        for (int dt = 0; dt < 4; ++dt) {
            union { unsigned short s[4]; uint2 u2; } w;
            #pragma unroll
            for (int r = 0; r < 4; ++r) w.s[r] = bf16bits(acc[u][dt][r] * inv);
            *(uint2*)(op + dt * 16 + kg * 4) = w.u2;
        }
    }
}
#else
// Fallback (round-5 structure); handles 128 q-rows as two sequential halves.
__global__ __launch_bounds__(256) void attn_mfma(const bf16* __restrict__ qkv,
                                                 const int* __restrict__ mask,
                                                 bf16* __restrict__ outp,
                                                 int B, int S, int LD) {
    const int h = blockIdx.y, b = blockIdx.z;
    const int Do = 1024;
    const int tid = threadIdx.x, lane = tid & 63, wid = tid >> 6;
    const int n = lane & 15, kg = lane >> 4;

    __shared__ bf16 Ks[64][66];
    __shared__ bf16 Vt[64][66];
    __shared__ bf16 Plds[4][16][66];
    __shared__ int  Msk[64];

    for (int half = 0; half < 2; ++half) {
        const int q0 = blockIdx.x * 128 + half * 64;
        __syncthreads();

        bf16x8 qf[2];
        {
            const bf16* qp = qkv + ((size_t)(b * S + q0 + wid * 16 + n)) * LD + h * 64 + kg * 8;
            union { uint4 u; bf16x8 v; } c0, c1;
            c0.u = *(const uint4*)qp;
            c1.u = *(const uint4*)(qp + 32);
            qf[0] = c0.v; qf[1] = c1.v;
        }

        f32x4 acc_o[4] = {};
        float m_r[4] = {-1e30f, -1e30f, -1e30f, -1e30f};
        float l_r[4] = {0.f, 0.f, 0.f, 0.f};

        const int sr = tid >> 2;
        const int sc = (tid & 3) * 16;
        const bf16* kbase = qkv + (size_t)(b * S) * LD + 1024 + h * 64;
        const bf16* vbase = qkv + (size_t)(b * S) * LD + 2048 + h * 64;

        for (int j0 = 0; j0 < S; j0 += 64) {
            __syncthreads();
            {
                const bf16* kp = kbase + (size_t)(j0 + sr) * LD + sc;
                uint4 ka = *(const uint4*)kp;
                uint4 kbv = *(const uint4*)(kp + 8);
                uint* kd = (uint*)((char*)&Ks[0][0] + sr * 132 + sc * 2);
                kd[0] = ka.x; kd[1] = ka.y; kd[2] = ka.z; kd[3] = ka.w;
                kd[4] = kbv.x; kd[5] = kbv.y; kd[6] = kbv.z; kd[7] = kbv.w;

                const bf16* vp = vbase + (size_t)(j0 + sr) * LD + sc;
                union { uint4 u[2]; unsigned short s[16]; } vv;
                vv.u[0] = *(const uint4*)vp;
                vv.u[1] = *(const uint4*)(vp + 8);
                #pragma unroll
                for (int i = 0; i < 16; ++i)
                    *((unsigned short*)((char*)&Vt[0][0] + (size_t)(sc + i) * 132 + sr * 2)) = vv.s[i];

                if (tid < 64) Msk[tid] = mask[b * S + j0 + tid];
            }
            __syncthreads();

            f32x4 st[4] = {};
            #pragma unroll
            for (int ks = 0; ks < 2; ++ks) {
                #pragma unroll
                for (int jt = 0; jt < 4; ++jt) {
                    union { uint u[4]; bf16x8 v; } bf;
                    const uint* bp = (const uint*)((const char*)&Ks[0][0]
                                     + (size_t)(jt * 16 + n) * 132 + ks * 64 + kg * 16);
                    bf.u[0] = bp[0]; bf.u[1] = bp[1]; bf.u[2] = bp[2]; bf.u[3] = bp[3];
                    st[jt] = __builtin_amdgcn_mfma_f32_16x16x32_bf16(qf[ks], bf.v, st[jt], 0, 0, 0);
                }
            }

            int mk[4];
            #pragma unroll
            for (int jt = 0; jt < 4; ++jt) mk[jt] = Msk[jt * 16 + n];

            #pragma unroll
            for (int r = 0; r < 4; ++r) {
                float mx = -1e30f;
                #pragma unroll
                for (int jt = 0; jt < 4; ++jt) {
                    float s = st[jt][r] * 0.125f;
                    if (mk[jt] == 0) s = -1e9f;
                    st[jt][r] = s;
                    mx = fmaxf(mx, s);
                }
                #pragma unroll
                for (int o = 1; o < 16; o <<= 1) mx = fmaxf(mx, __shfl_xor(mx, o, 64));
                float newm = fmaxf(m_r[r], mx);
                float alpha = __expf(m_r[r] - newm);
                m_r[r] = newm;
                float ls = 0.f;
                #pragma unroll
                for (int jt = 0; jt < 4; ++jt) {
                    float p = __expf(st[jt][r] - newm);
                    ls += p;
                    Plds[wid][kg * 4 + r][jt * 16 + n] = __float2bfloat16(p);
                }
                #pragma unroll
                for (int o = 1; o < 16; o <<= 1) ls += __shfl_xor(ls, o, 64);
                l_r[r] = l_r[r] * alpha + ls;
                #pragma unroll
                for (int dt = 0; dt < 4; ++dt) acc_o[dt][r] *= alpha;
            }

            __asm__ volatile("s_waitcnt lgkmcnt(0)" ::: "memory");

            #pragma unroll
            for (int ks = 0; ks < 2; ++ks) {
                union { uint u[4]; bf16x8 v; } af;
                const uint* ap = (const uint*)((const char*)&Plds[wid][0][0]
                                 + (size_t)n * 132 + ks * 64 + kg * 16);
                af.u[0] = ap[0]; af.u[1] = ap[1]; af.u[2] = ap[2]; af.u[3] = ap[3];
                #pragma unroll
                for (int dt = 0; dt < 4; ++dt) {
                    union { uint u[4]; bf16x8 v; } bf;
                    const uint* bp = (const uint*)((const char*)&Vt[0][0]
                                     + (size_t)(dt * 16 + n) * 132 + ks * 64 + kg * 16);
                    bf.u[0] = bp[0]; bf.u[1] = bp[1]; bf.u[2] = bp[2]; bf.u[3] = bp[3];
                    acc_o[dt] = __builtin_amdgcn_mfma_f32_16x16x32_bf16(af.v, bf.v, acc_o[dt], 0, 0, 0);
                }
            }
        }

        #pragma unroll
        for (int r = 0; r < 4; ++r) {
            float inv = (l_r[r] > 0.f) ? (1.f / l_r[r]) : 0.f;
            bf16* op = outp + ((size_t)(b * S + q0 + wid * 16 + kg * 4 + r)) * Do + h * 64 + n;
            #pragma unroll
            for (int dt = 0; dt < 4; ++dt)
                op[dt * 16] = __float2bfloat16(acc_o[dt][r] * inv);
        }
    }
}
#endif

extern "C" void kernel_launch(void* const* d_in, const int* in_sizes, int n_in,
                              void* d_out, int out_size, void* d_ws, size_t ws_size,
                              hipStream_t stream) {
    const int B = 2, S = 2048, D = 1024, H = 16, F = 4096;
    const int M = B * S;  // 4096

    const float* x   = (const float*)d_in[0];
    const int*   mask= (const int*)  d_in[1];
    const float* wq  = (const float*)d_in[2];
    const float* bq  = (const float*)d_in[3];
    const float* wk  = (const float*)d_in[4];
    const float* bk  = (const float*)d_in[5];
    const float* wv  = (const float*)d_in[6];
    const float* bv  = (const float*)d_in[7];
    const float* wo  = (const float*)d_in[8];
    const float* bo  = (const float*)d_in[9];
    const float* g1  = (const float*)d_in[10];
    const float* be1 = (const float*)d_in[11];
    const float* g2  = (const float*)d_in[12];
    const float* be2 = (const float*)d_in[13];
    const float* w1  = (const float*)d_in[14];
    const float* bf1 = (const float*)d_in[15];
    const float* w2  = (const float*)d_in[16];
    const float* bf2 = (const float*)d_in[17];
    float* out = (float*)d_out;

    char* ws = (char*)d_ws;
    const size_t MB = 1024 * 1024;
    bf16* wqkvT = (bf16*)(ws + 0 * MB);            // [3072,1024]
    bf16* woT   = (bf16*)(ws + 6 * MB);
    bf16* w1T   = (bf16*)(ws + 8 * MB);
    bf16* w2T   = (bf16*)(ws + 16 * MB);
    bf16* xn    = (bf16*)(ws + 24 * MB);
    bf16* qkv   = (bf16*)(ws + 32 * MB);           // [4096,3072]
    bf16* att   = xn;                              // reuse
    // x2 (fp32 residual carrier) lives in d_out.

    const bool fullM = (ws_size >= 64 * MB);

    transpose_all<<<12288, 256, 0, stream>>>(wq, wk, wv, wo, w1, w2,
                                             wqkvT, woT, w1T, w2T);

    ln_kernel<float><<<M, 256, 0, stream>>>(x, g1, be1, xn, D);

    gemm_mfma<128, bf16, float, false, false, true><<<dim3(3072 / 128, M / 128), 256, 0, stream>>>(
        xn, wqkvT, bq, bk, bv, (const float*)nullptr, qkv, M, 3072, D);

    attn_mfma<<<dim3(S / 128, H, B), 256, 0, stream>>>(qkv, mask, att, B, S, 3072);

    gemm_mfma<64, float, float, false, true, false><<<dim3(D / 128, M / 64), 256, 0, stream>>>(
        att, woT, bo, nullptr, nullptr, x, out, M, D, D);

    if (fullM) {
        bf16* hid = (bf16*)(ws + 24 * MB);   // [4096,4096] at [24,56)
        bf16* xn2 = (bf16*)(ws + 56 * MB);   // [4096,1024] at [56,64)
        ln_kernel<float><<<M, 256, 0, stream>>>(out, g2, be2, xn2, D);
        gemm_mfma256<true><<<dim3(F / 256, M / 256), 512, 0, stream>>>(
            xn2, w1T, bf1, hid, M, F, D);
        gemm_mfma<64, float, float, false, true, false><<<dim3(D / 128, M / 64), 256, 0, stream>>>(
            hid, w2T, bf2, nullptr, nullptr, out, out, M, D, F);
    } else {
        bf16* xn2 = (bf16*)(ws + 32 * MB);   // q-section reuse
        bf16* hid = (bf16*)(ws + 40 * MB);   // k+v sections, [2048,4096]
        const int CH = 2048;
        ln_kernel<float><<<M, 256, 0, stream>>>(out, g2, be2, xn2, D);
        for (int c = 0; c < M / CH; ++c) {
            const size_t roff = (size_t)c * CH;
            gemm_mfma<128, bf16, float, true, false, false><<<dim3(F / 128, CH / 128), 256, 0, stream>>>(
                xn2 + roff * D, w1T, bf1, nullptr, nullptr, (const float*)nullptr, hid, CH, F, D);
            gemm_mfma<64, float, float, false, true, false><<<dim3(D / 128, CH / 64), 256, 0, stream>>>(
                hid, w2T, bf2, nullptr, nullptr, out + roff * D, out + roff * D, CH, D, F);
        }
    }
}

// Round 7
// 380.799 us; speedup vs baseline: 1.0679x; 1.0176x over previous
//
#include <hip/hip_runtime.h>
#include <hip/hip_bf16.h>

// Transformer block: LN1 -> QKV -> MHA(16 heads, hd=64) -> out-proj + resid
//                    -> LN2 -> FFN(4x, ReLU) + resid
// B=2, S=2048, D=1024, H=16, hd=64, F=4096. M = B*S = 4096.
// fp32 buffers in/out; bf16 intermediates (fp32 accumulation).
//
// Round 17: round-16's flash-decoding j-split crashed (GPU fault /
// harness tripwire around d_out-as-scratch; cause not isolated) -> full
// revert to the round-15 base (387.5us known good). This round, one safe
// change in attn: K-path rework on the proven GEMM LDS pattern.
//  - K staging via async16 (global_load_lds) direct to a linear [64][64]
//    Ks with pre-swizzled global source (srow=lane>>3, scol=((lane&7)^srow)*8)
//    -- removes the K reg round-trip + 8 ds_write_b32/thread.
//  - K-frag reads become ONE ds_read_b128 at slot (ks*4+kg)^(n&7)
//    (was 4x ds_read_b32 at 132B stride, 32 reads/tile/wave -> 8).
//  - Safety: __syncthreads() lowers to s_waitcnt vmcnt(0); s_barrier, so
//    each tile's K-asyncs (issued after the PREVIOUS barrier) are complete
//    block-wide before any read. Same pipeline depth as before.
// V staging/softmax/PV/mask-skip/defer-max unchanged (round-12 logic).
// FFN1 keeps the 256^2 8-phase gemm256. GEMM 128^2 BK=64 XOR unchanged.

using bf16 = __hip_bfloat16;
typedef short bf16x8 __attribute__((ext_vector_type(8)));
typedef short bf16x4v __attribute__((ext_vector_type(4)));
typedef float f32x4 __attribute__((ext_vector_type(4)));

#if defined(__has_builtin)
#  if __has_builtin(__builtin_amdgcn_mfma_f32_16x16x16bf16_1k)
#    define HAVE_MFMA_K16 1
#  endif
#  if __has_builtin(__builtin_amdgcn_exp2f)
#    define EXP2F(x) __builtin_amdgcn_exp2f(x)
#  endif
#  if __has_builtin(__builtin_amdgcn_sched_barrier)
#    define SCHED_BARRIER() __builtin_amdgcn_sched_barrier(0)
#  endif
#  if __has_builtin(__builtin_amdgcn_s_setprio)
#    define SETPRIO(x) __builtin_amdgcn_s_setprio(x)
#  endif
#endif
#ifndef EXP2F
#  define EXP2F(x) __expf(0.6931471805599453f * (x))
#endif
#ifndef SCHED_BARRIER
#  define SCHED_BARRIER()
#endif
#ifndef SETPRIO
#  define SETPRIO(x)
#endif

__device__ __forceinline__ float toF(float v) { return v; }
__device__ __forceinline__ float toF(bf16 v) { return __bfloat162float(v); }
__device__ __forceinline__ void storeF(float* p, float v) { *p = v; }
__device__ __forceinline__ void storeF(bf16* p, float v) { *p = __float2bfloat16(v); }

__device__ __forceinline__ float waveReduceSum(float v) {
    #pragma unroll
    for (int o = 32; o > 0; o >>= 1) v += __shfl_down(v, o, 64);
    return v;
}

__device__ __forceinline__ void async16(const bf16* g, bf16* l) {
    __builtin_amdgcn_global_load_lds(
        (const __attribute__((address_space(1))) unsigned int*)g,
        (__attribute__((address_space(3))) unsigned int*)l,
        16, 0, 0);
}

__device__ __forceinline__ unsigned short bf16bits(float x) {
    union { bf16 h; unsigned short u; } e; e.h = __float2bfloat16(x);
    return e.u;
}

// ---------------- fused weight transpose + cast (all 6 weights) ------------
__global__ __launch_bounds__(256) void transpose_all(
        const float* __restrict__ wq, const float* __restrict__ wk,
        const float* __restrict__ wv, const float* __restrict__ wo,
        const float* __restrict__ w1, const float* __restrict__ w2,
        bf16* __restrict__ wqkvT, bf16* __restrict__ woT,
        bf16* __restrict__ w1T, bf16* __restrict__ w2T) {
    __shared__ float t[32][33];
    const int tI = blockIdx.x;
    const float* in; bf16* outT; int R, C, tl;
    if (tI < 4096) {
        const int seg = tI >> 10; tl = tI & 1023; R = 1024; C = 1024;
        in = (seg == 0) ? wq : (seg == 1) ? wk : (seg == 2) ? wv : wo;
        outT = (seg == 3) ? woT : wqkvT + (size_t)seg * 1024 * 1024;
    } else if (tI < 8192) {
        tl = tI - 4096; in = w1; outT = w1T; R = 1024; C = 4096;
    } else {
        tl = tI - 8192; in = w2; outT = w2T; R = 4096; C = 1024;
    }
    const int tc = C >> 5;
    const int c0 = (tl % tc) * 32, r0 = (tl / tc) * 32;
    const int lx = threadIdx.x & 31, ly = threadIdx.x >> 5;
    #pragma unroll
    for (int i = 0; i < 32; i += 8)
        t[ly + i][lx] = in[(size_t)(r0 + ly + i) * C + c0 + lx];
    __syncthreads();
    #pragma unroll
    for (int i = 0; i < 32; i += 8)
        outT[(size_t)(c0 + ly + i) * R + r0 + lx] = __float2bfloat16(t[lx][ly + i]);
}

// ---------------- LayerNorm: InT x -> bf16 out ----------------
template <typename InT>
__global__ __launch_bounds__(256) void ln_kernel(const InT* __restrict__ x,
                                                 const float* __restrict__ g,
                                                 const float* __restrict__ b,
                                                 bf16* __restrict__ out, int D) {
    const int row = blockIdx.x;
    const InT* xr = x + (size_t)row * D;
    float s = 0.f, s2 = 0.f;
    for (int i = threadIdx.x; i < D; i += 256) {
        float v = toF(xr[i]);
        s += v; s2 += v * v;
    }
    __shared__ float ws[4], ws2[4];
    int lane = threadIdx.x & 63, wid = threadIdx.x >> 6;
    s = waveReduceSum(s); s2 = waveReduceSum(s2);
    if (lane == 0) { ws[wid] = s; ws2[wid] = s2; }
    __syncthreads();
    float ts = ws[0] + ws[1] + ws[2] + ws[3];
    float ts2 = ws2[0] + ws2[1] + ws2[2] + ws2[3];
    float mean = ts / D;
    float var = ts2 / D - mean * mean;
    float rstd = rsqrtf(var + 1e-5f);
    bf16* outr = out + (size_t)row * D;
    for (int i = threadIdx.x; i < D; i += 256) {
        float v = (toF(xr[i]) - mean) * rstd * g[i] + b[i];
        outr[i] = __float2bfloat16(v);
    }
}

// ---------------- MFMA GEMM: C = act(A @ BT^T + bias) [+ resid] ------------
// BK=64, XOR-swizzled LDS (chunk c of row r stored at slot c^(r&7)).
template <int BM, typename OutT, typename ResidT, bool RELU, bool HAS_RESID, bool BIAS3>
__global__ __launch_bounds__(256) void gemm_mfma(const bf16* __restrict__ A,
                                                 const bf16* __restrict__ BT,
                                                 const float* __restrict__ bias,
                                                 const float* __restrict__ biasK,
                                                 const float* __restrict__ biasV,
                                                 const ResidT* __restrict__ resid,
                                                 OutT* __restrict__ C,
                                                 int M, int N, int K) {
    constexpr int BK = 64;
    constexpr int MI = BM / 32;
    constexpr int AROWS = BM / 4;
    constexpr int ASEC = AROWS / 8;
    __shared__ bf16 As[BM][BK];      // row stride 128 B
    __shared__ bf16 Bs[128][BK];
    const int tid = threadIdx.x, lane = tid & 63, wid = tid >> 6;
    const int m0 = blockIdx.y * BM, n0 = blockIdx.x * 128;
    const int wm = (BM == 128) ? (wid >> 1) * 64 : (wid & 1) * 32;
    const int wn = (BM == 128) ? (wid & 1) * 64 : (wid >> 1) * 64;

    f32x4 acc[MI][4] = {};

    const int srow = lane >> 3;
    const int scol = ((lane & 7) ^ srow) * 8;
    const bf16* Abase = A + (size_t)(m0 + wid * AROWS + srow) * K + scol;
    const bf16* Bbase = BT + (size_t)(n0 + wid * 32 + srow) * K + scol;

    const int fr = lane & 15;
    const int kg = lane >> 4;

    for (int k0 = 0; k0 < K; k0 += BK) {
        #pragma unroll
        for (int s = 0; s < ASEC; ++s)
            async16(Abase + (size_t)(s * 8) * K + k0, &As[wid * AROWS + s * 8][0]);
        #pragma unroll
        for (int s = 0; s < 4; ++s)
            async16(Bbase + (size_t)(s * 8) * K + k0, &Bs[wid * 32 + s * 8][0]);
        __syncthreads();

        #pragma unroll
        for (int ks = 0; ks < 2; ++ks) {
            const int pc = ((ks * 4 + kg) ^ (fr & 7)) * 16;
            bf16x8 aF[MI], bF[4];
            #pragma unroll
            for (int i = 0; i < MI; ++i)
                aF[i] = *(const bf16x8*)((const char*)&As[0][0]
                         + (size_t)(wm + i * 16 + fr) * 128 + pc);
            #pragma unroll
            for (int j = 0; j < 4; ++j)
                bF[j] = *(const bf16x8*)((const char*)&Bs[0][0]
                         + (size_t)(wn + j * 16 + fr) * 128 + pc);
            #pragma unroll
            for (int i = 0; i < MI; ++i)
                #pragma unroll
                for (int j = 0; j < 4; ++j)
                    acc[i][j] = __builtin_amdgcn_mfma_f32_16x16x32_bf16(
                        aF[i], bF[j], acc[i][j], 0, 0, 0);
        }
        __syncthreads();
    }

    const int col_l = lane & 15, row_l = (lane >> 4) * 4;
    #pragma unroll
    for (int j = 0; j < 4; ++j) {
        const int col = n0 + wn + j * 16 + col_l;
        float bvv;
        if (BIAS3) {
            const float* bp = (col < 1024) ? bias : ((col < 2048) ? biasK : biasV);
            bvv = bp[col & 1023];
        } else {
            bvv = bias[col];
        }
        #pragma unroll
        for (int i = 0; i < MI; ++i) {
            #pragma unroll
            for (int r = 0; r < 4; ++r) {
                const int row = m0 + wm + i * 16 + row_l + r;
                float v = acc[i][j][r] + bvv;
                if (RELU) v = fmaxf(v, 0.f);
                if (HAS_RESID) v += toF(resid[(size_t)row * N + col]);
                storeF(&C[(size_t)row * N + col], v);
            }
        }
    }
}

// ---------------- 256x256 8-phase MFMA GEMM (T2+T3+T4+T5) ------------------
// 512 threads / 8 waves (2M x 4N); per-wave output 128x64; BK=64.
// Double-buffered 128KB LDS; 4 phases per K-tile; counted vmcnt (drain only
// at phase 3, for stages issued >=2 phases earlier); raw s_barrier; setprio
// around each 16-MFMA cluster.
template <bool RELU>
__global__ __launch_bounds__(512, 1) void gemm_mfma256(const bf16* __restrict__ A,
                                                       const bf16* __restrict__ BT,
                                                       const float* __restrict__ bias,
                                                       bf16* __restrict__ C,
                                                       int M, int N, int K) {
    constexpr int BK = 64;
    __shared__ bf16 As[2][256][BK];
    __shared__ bf16 Bs[2][256][BK];
    const int tid = threadIdx.x, lane = tid & 63, wid = tid >> 6;
    const int m0 = blockIdx.y * 256, n0 = blockIdx.x * 256;
    const int wm = (wid >> 2) * 128, wn = (wid & 3) * 64;

    f32x4 acc[8][4] = {};

    const int srow = lane >> 3;
    const int scol = ((lane & 7) ^ srow) * 8;   // pre-swizzled source chunk
    const bf16* Abase = A + (size_t)(m0 + wid * 16 + srow) * K + scol;
    const bf16* Bbase = BT + (size_t)(n0 + wid * 16 + srow) * K + scol;

    const int fr = lane & 15;
    const int kg = lane >> 4;
    const int NT = K / BK;

    // prologue: stage tile 0 into buf 0
    #pragma unroll
    for (int h = 0; h < 2; ++h)
        #pragma unroll
        for (int s = 0; s < 2; ++s) {
            async16(Abase + (size_t)(h * 128 + s * 8) * K,
                    &As[0][h * 128 + wid * 16 + s * 8][0]);
            async16(Bbase + (size_t)(h * 128 + s * 8) * K,
                    &Bs[0][h * 128 + wid * 16 + s * 8][0]);
        }
    asm volatile("s_waitcnt vmcnt(0)" ::: "memory");
    __builtin_amdgcn_s_barrier();
    SCHED_BARRIER();

    for (int t = 0; t < NT; ++t) {
        const int cur = t & 1;
        const size_t k1 = (size_t)(t + 1) * BK;
        const char* ab = (const char*)&As[cur][0][0];
        const char* bb = (const char*)&Bs[cur][0][0];
        const bool pf = (t + 1 < NT);
        bf16x8 aF[4][2], bF[4][2];

        // ---- phase 0: read A rows0-3 + B cols0-1; stage next A ----
        #pragma unroll
        for (int i = 0; i < 4; ++i)
            #pragma unroll
            for (int kk = 0; kk < 2; ++kk)
                aF[i][kk] = *(const bf16x8*)(ab + (size_t)(wm + i * 16 + fr) * 128
                                             + ((kk * 4 + kg) ^ (fr & 7)) * 16);
        #pragma unroll
        for (int j = 0; j < 2; ++j)
            #pragma unroll
            for (int kk = 0; kk < 2; ++kk)
                bF[j][kk] = *(const bf16x8*)(bb + (size_t)(wn + j * 16 + fr) * 128
                                             + ((kk * 4 + kg) ^ (fr & 7)) * 16);
        if (pf) {
            #pragma unroll
            for (int h = 0; h < 2; ++h)
                #pragma unroll
                for (int s = 0; s < 2; ++s)
                    async16(Abase + (size_t)(h * 128 + s * 8) * K + k1,
                            &As[cur ^ 1][h * 128 + wid * 16 + s * 8][0]);
        }
        __builtin_amdgcn_s_barrier();
        SCHED_BARRIER();
        SETPRIO(1);
        #pragma unroll
        for (int i = 0; i < 4; ++i)
            #pragma unroll
            for (int j = 0; j < 2; ++j)
                #pragma unroll
                for (int kk = 0; kk < 2; ++kk)
                    acc[i][j] = __builtin_amdgcn_mfma_f32_16x16x32_bf16(
                        aF[i][kk], bF[j][kk], acc[i][j], 0, 0, 0);
        SETPRIO(0);

        // ---- phase 1: read B cols2-3; stage next B ----
        #pragma unroll
        for (int j = 2; j < 4; ++j)
            #pragma unroll
            for (int kk = 0; kk < 2; ++kk)
                bF[j][kk] = *(const bf16x8*)(bb + (size_t)(wn + j * 16 + fr) * 128
                                             + ((kk * 4 + kg) ^ (fr & 7)) * 16);
        if (pf) {
            #pragma unroll
            for (int h = 0; h < 2; ++h)
                #pragma unroll
                for (int s = 0; s < 2; ++s)
                    async16(Bbase + (size_t)(h * 128 + s * 8) * K + k1,
                            &Bs[cur ^ 1][h * 128 + wid * 16 + s * 8][0]);
        }
        __builtin_amdgcn_s_barrier();
        SCHED_BARRIER();
        SETPRIO(1);
        #pragma unroll
        for (int i = 0; i < 4; ++i)
            #pragma unroll
            for (int j = 2; j < 4; ++j)
                #pragma unroll
                for (int kk = 0; kk < 2; ++kk)
                    acc[i][j] = __builtin_amdgcn_mfma_f32_16x16x32_bf16(
                        aF[i][kk], bF[j][kk], acc[i][j], 0, 0, 0);
        SETPRIO(0);

        // ---- phase 2: read A rows4-7 (reuse aF regs) ----
        #pragma unroll
        for (int i = 0; i < 4; ++i)
            #pragma unroll
            for (int kk = 0; kk < 2; ++kk)
                aF[i][kk] = *(const bf16x8*)(ab + (size_t)(wm + (i + 4) * 16 + fr) * 128
                                             + ((kk * 4 + kg) ^ (fr & 7)) * 16);
        __builtin_amdgcn_s_barrier();
        SCHED_BARRIER();
        SETPRIO(1);
        #pragma unroll
        for (int i = 0; i < 4; ++i)
            #pragma unroll
            for (int j = 0; j < 2; ++j)
                #pragma unroll
                for (int kk = 0; kk < 2; ++kk)
                    acc[i + 4][j] = __builtin_amdgcn_mfma_f32_16x16x32_bf16(
                        aF[i][kk], bF[j][kk], acc[i + 4][j], 0, 0, 0);
        SETPRIO(0);

        // ---- phase 3: publish next tile (vmcnt for stages issued in ph0/1) -
        if (pf) asm volatile("s_waitcnt vmcnt(0)" ::: "memory");
        __builtin_amdgcn_s_barrier();
        SCHED_BARRIER();
        SETPRIO(1);
        #pragma unroll
        for (int i = 0; i < 4; ++i)
            #pragma unroll
            for (int j = 2; j < 4; ++j)
                #pragma unroll
                for (int kk = 0; kk < 2; ++kk)
                    acc[i + 4][j] = __builtin_amdgcn_mfma_f32_16x16x32_bf16(
                        aF[i][kk], bF[j][kk], acc[i + 4][j], 0, 0, 0);
        SETPRIO(0);
    }

    // ---- epilogue: bias (+ReLU), bf16 store ----
    const int col_l = lane & 15, row_l = (lane >> 4) * 4;
    #pragma unroll
    for (int j = 0; j < 4; ++j) {
        const int col = n0 + wn + j * 16 + col_l;
        const float bvv = bias[col];
        #pragma unroll
        for (int i = 0; i < 8; ++i) {
            #pragma unroll
            for (int r = 0; r < 4; ++r) {
                const int row = m0 + wm + i * 16 + row_l + r;
                float v = acc[i][j][r] + bvv;
                if (RELU) v = fmaxf(v, 0.f);
                C[(size_t)row * N + col] = __float2bfloat16(v);
            }
        }
    }
}

// ---------------- MFMA flash attention, S^T formulation, TQ=128 ------------
// Round-12 logic; round-17 K-path: K staged via async16 (global_load_lds)
// into linear [64][64] Ks with GEMM-style XOR chunk swizzle; K-frag reads
// are single ds_read_b128. V keeps reg-staged transpose (T14).
#if HAVE_MFMA_K16
__global__ __launch_bounds__(256) void attn_mfma(const bf16* __restrict__ qkv,
                                                 const int* __restrict__ mask,
                                                 bf16* __restrict__ outp,
                                                 int B, int S, int LD) {
    const int q0 = blockIdx.x * 128;
    const int h = blockIdx.y, b = blockIdx.z;
    const int Do = 1024;
    const int tid = threadIdx.x, lane = tid & 63, wid = tid >> 6;
    const int n = lane & 15, kg = lane >> 4;

    __shared__ bf16 Ks[2][64][64];   // K tile [j][d], 128B rows, XOR chunks
    __shared__ bf16 Vt[2][64][68];   // V^T tile [d][j], 136B rows
    __shared__ float Mskf[2][64];    // additive mask bias (log2 domain)
    __shared__ int sAny[2];          // any masked position in this j-tile?

    // Q B-frags, pre-scaled by (1/sqrt(64))*log2(e); wave owns 32 q-rows.
    const float QSCALE = 0.125f * 1.4426950408889634f;
    bf16x8 qf[2][2];
    #pragma unroll
    for (int u = 0; u < 2; ++u) {
        const bf16* qp = qkv + ((size_t)(b * S + q0 + wid * 32 + u * 16 + n)) * LD + h * 64 + kg * 8;
        union { uint4 uu; bf16x8 v; unsigned short s[8]; } c[2];
        c[0].uu = *(const uint4*)qp;
        c[1].uu = *(const uint4*)(qp + 32);
        #pragma unroll
        for (int t = 0; t < 2; ++t) {
            #pragma unroll
            for (int i = 0; i < 8; ++i) {
                union { float f; unsigned int u2; } d;
                d.u2 = ((unsigned int)c[t].s[i]) << 16;
                c[t].s[i] = bf16bits(d.f * QSCALE);
            }
            qf[u][t] = c[t].v;
        }
    }

    f32x4 acc[2][4] = {};
    float m[2] = {-1e30f, -1e30f}, l[2] = {0.f, 0.f};

    const int jp = tid & 31, dg = (tid >> 5) * 8;
    const bf16* kbase = qkv + (size_t)(b * S) * LD + 1024 + h * 64;
    const bf16* vbase = qkv + (size_t)(b * S) * LD + 2048 + h * 64;

    // K async staging: pre-swizzled per-lane global source (GEMM pattern).
    const int srow = lane >> 3;
    const int scol = ((lane & 7) ^ srow) * 8;
    const bf16* kAsy = kbase + (size_t)(wid * 16 + srow) * LD + scol;

    // staged V registers (T14 issue-early / write-late)
    uint4 vau, vcu;
    int mz = 0;

    // prologue: K tile-0 async -> Ks[0]; V tile-0 + mask -> regs
    {
        #pragma unroll
        for (int s = 0; s < 2; ++s)
            async16(kAsy + (size_t)(s * 8) * LD, &Ks[0][wid * 16 + s * 8][0]);
        const bf16* vp = vbase + (size_t)(2 * jp) * LD + dg;
        vau = *(const uint4*)vp;
        vcu = *(const uint4*)(vp + LD);
        if (tid < 64) mz = (mask[b * S + tid] == 0);
    }

    const int NT = S / 64;
    for (int t = 0; t < NT; ++t) {
        const int cur = t & 1;

        // ---- write staged V tile t into LDS buf[cur]; mask bias ----
        {
            union { uint4 u4; unsigned short s[8]; } va, vc;
            va.u4 = vau; vc.u4 = vcu;
            #pragma unroll
            for (int i = 0; i < 8; ++i) {
                unsigned int pk = (unsigned int)va.s[i] | ((unsigned int)vc.s[i] << 16);
                *(unsigned int*)((char*)&Vt[cur][0][0] + (size_t)(dg + i) * 136 + jp * 4) = pk;
            }
            if (tid < 64) {
                Mskf[cur][tid] = mz ? -1e9f : 0.f;
                unsigned long long bl = __ballot(mz);
                if (tid == 0) sAny[cur] = (bl != 0ull) ? 1 : 0;
            }
        }
        // __syncthreads lowers to s_waitcnt vmcnt(0) lgkmcnt(0); s_barrier:
        // drains this buffer's K-asyncs block-wide before any wave reads Ks[cur].
        __syncthreads();

        // ---- issue tile t+1: K async -> Ks[cur^1]; V + mask -> regs -------
        if (t + 1 < NT) {
            const int j0 = (t + 1) * 64;
            #pragma unroll
            for (int s = 0; s < 2; ++s)
                async16(kAsy + (size_t)(j0 + s * 8) * LD, &Ks[cur ^ 1][wid * 16 + s * 8][0]);
            const bf16* vp = vbase + (size_t)(j0 + 2 * jp) * LD + dg;
            vau = *(const uint4*)vp;
            vcu = *(const uint4*)(vp + LD);
            if (tid < 64) mz = (mask[b * S + j0 + tid] == 0);
        }

        // ---- S^T = K @ Q^T (log2-scaled); K-frags: 1x ds_read_b128 each ---
        f32x4 st[2][4] = {};
        #pragma unroll
        for (int ks = 0; ks < 2; ++ks) {
            #pragma unroll
            for (int jt = 0; jt < 4; ++jt) {
                bf16x8 kf = *(const bf16x8*)((const char*)&Ks[cur][0][0]
                             + (size_t)(jt * 16 + n) * 128
                             + (size_t)(((ks * 4 + kg) ^ (n & 7)) * 16));
                st[0][jt] = __builtin_amdgcn_mfma_f32_16x16x32_bf16(kf, qf[0][ks], st[0][jt], 0, 0, 0);
                st[1][jt] = __builtin_amdgcn_mfma_f32_16x16x32_bf16(kf, qf[1][ks], st[1][jt], 0, 0, 0);
            }
        }

        // ---- mask bias only when the tile actually has masked positions ---
        if (sAny[cur]) {
            #pragma unroll
            for (int u = 0; u < 2; ++u) {
                #pragma unroll
                for (int jt = 0; jt < 4; ++jt) {
                    f32x4 mb = *(const f32x4*)&Mskf[cur][jt * 16 + kg * 4];
                    #pragma unroll
                    for (int r = 0; r < 4; ++r) st[u][jt][r] += mb[r];
                }
            }
        }

        // ---- online softmax with defer-max (THR=8 in log2 domain) ---------
        float mx0 = st[0][0][0], mx1 = st[1][0][0];
        #pragma unroll
        for (int jt = 0; jt < 4; ++jt) {
            #pragma unroll
            for (int r = 0; r < 4; ++r) {
                mx0 = fmaxf(mx0, st[0][jt][r]);
                mx1 = fmaxf(mx1, st[1][jt][r]);
            }
        }
        mx0 = fmaxf(mx0, __shfl_xor(mx0, 16, 64));
        mx0 = fmaxf(mx0, __shfl_xor(mx0, 32, 64));
        mx1 = fmaxf(mx1, __shfl_xor(mx1, 16, 64));
        mx1 = fmaxf(mx1, __shfl_xor(mx1, 32, 64));

        if (__any((mx0 > m[0] + 8.f) || (mx1 > m[1] + 8.f))) {
            float mxa[2] = {mx0, mx1};
            #pragma unroll
            for (int u = 0; u < 2; ++u) {
                float newm = fmaxf(m[u], mxa[u]);
                float alpha = EXP2F(m[u] - newm);
                m[u] = newm;
                l[u] *= alpha;
                #pragma unroll
                for (int dt = 0; dt < 4; ++dt)
                    #pragma unroll
                    for (int r = 0; r < 4; ++r) acc[u][dt][r] *= alpha;
            }
        }

        bf16x4v pf[2][4];
        #pragma unroll
        for (int u = 0; u < 2; ++u) {
            float ls = 0.f;
            #pragma unroll
            for (int jt = 0; jt < 4; ++jt) {
                union { unsigned short s[4]; bf16x4v v; } pk;
                #pragma unroll
                for (int r = 0; r < 4; ++r) {
                    union { float f; unsigned int u2; } p;
                    p.f = EXP2F(st[u][jt][r] - m[u]);
                    p.u2 &= 0xffff0000u;          // truncate to bf16
                    ls += p.f;                    // sum the truncated value
                    pk.s[r] = (unsigned short)(p.u2 >> 16);
                }
                pf[u][jt] = pk.v;
            }
            ls += __shfl_xor(ls, 16, 64);
            ls += __shfl_xor(ls, 32, 64);
            l[u] += ls;
        }

        // ---- O^T += V^T @ P^T; V-frags read once ----
        #pragma unroll
        for (int jt = 0; jt < 4; ++jt) {
            #pragma unroll
            for (int dt = 0; dt < 4; ++dt) {
                union { uint u[2]; bf16x4v v; } vf;
                const uint* vpp = (const uint*)((const char*)&Vt[cur][0][0]
                                  + (size_t)(dt * 16 + n) * 136 + jt * 32 + kg * 8);
                vf.u[0] = vpp[0]; vf.u[1] = vpp[1];
                acc[0][dt] = __builtin_amdgcn_mfma_f32_16x16x16bf16_1k(vf.v, pf[0][jt], acc[0][dt], 0, 0, 0);
                acc[1][dt] = __builtin_amdgcn_mfma_f32_16x16x16bf16_1k(vf.v, pf[1][jt], acc[1][dt], 0, 0, 0);
            }
        }
    }

    // ---- epilogue ----
    #pragma unroll
    for (int u = 0; u < 2; ++u) {
        float inv = (l[u] > 0.f) ? (1.f / l[u]) : 0.f;
        bf16* op = outp + ((size_t)(b * S + q0 + wid * 32 + u * 16 + n)) * Do + h * 64;
        #pragma unroll
        for (int dt = 0; dt < 4; ++dt) {
            union { unsigned short s[4]; uint2 u2; } w;
            #pragma unroll
            for (int r = 0; r < 4; ++r) w.s[r] = bf16bits(acc[u][dt][r] * inv);
            *(uint2*)(op + dt * 16 + kg * 4) = w.u2;
        }
    }
}
#else
// Fallback (round-5 structure); handles 128 q-rows as two sequential halves.
__global__ __launch_bounds__(256) void attn_mfma(const bf16* __restrict__ qkv,
                                                 const int* __restrict__ mask,
                                                 bf16* __restrict__ outp,
                                                 int B, int S, int LD) {
    const int h = blockIdx.y, b = blockIdx.z;
    const int Do = 1024;
    const int tid = threadIdx.x, lane = tid & 63, wid = tid >> 6;
    const int n = lane & 15, kg = lane >> 4;

    __shared__ bf16 Ks[64][66];
    __shared__ bf16 Vt[64][66];
    __shared__ bf16 Plds[4][16][66];
    __shared__ int  Msk[64];

    for (int half = 0; half < 2; ++half) {
        const int q0 = blockIdx.x * 128 + half * 64;
        __syncthreads();

        bf16x8 qf[2];
        {
            const bf16* qp = qkv + ((size_t)(b * S + q0 + wid * 16 + n)) * LD + h * 64 + kg * 8;
            union { uint4 u; bf16x8 v; } c0, c1;
            c0.u = *(const uint4*)qp;
            c1.u = *(const uint4*)(qp + 32);
            qf[0] = c0.v; qf[1] = c1.v;
        }

        f32x4 acc_o[4] = {};
        float m_r[4] = {-1e30f, -1e30f, -1e30f, -1e30f};
        float l_r[4] = {0.f, 0.f, 0.f, 0.f};

        const int sr = tid >> 2;
        const int sc = (tid & 3) * 16;
        const bf16* kbase = qkv + (size_t)(b * S) * LD + 1024 + h * 64;
        const bf16* vbase = qkv + (size_t)(b * S) * LD + 2048 + h * 64;

        for (int j0 = 0; j0 < S; j0 += 64) {
            __syncthreads();
            {
                const bf16* kp = kbase + (size_t)(j0 + sr) * LD + sc;
                uint4 ka = *(const uint4*)kp;
                uint4 kbv = *(const uint4*)(kp + 8);
                uint* kd = (uint*)((char*)&Ks[0][0] + sr * 132 + sc * 2);
                kd[0] = ka.x; kd[1] = ka.y; kd[2] = ka.z; kd[3] = ka.w;
                kd[4] = kbv.x; kd[5] = kbv.y; kd[6] = kbv.z; kd[7] = kbv.w;

                const bf16* vp = vbase + (size_t)(j0 + sr) * LD + sc;
                union { uint4 u[2]; unsigned short s[16]; } vv;
                vv.u[0] = *(const uint4*)vp;
                vv.u[1] = *(const uint4*)(vp + 8);
                #pragma unroll
                for (int i = 0; i < 16; ++i)
                    *((unsigned short*)((char*)&Vt[0][0] + (size_t)(sc + i) * 132 + sr * 2)) = vv.s[i];

                if (tid < 64) Msk[tid] = mask[b * S + j0 + tid];
            }
            __syncthreads();

            f32x4 st[4] = {};
            #pragma unroll
            for (int ks = 0; ks < 2; ++ks) {
                #pragma unroll
                for (int jt = 0; jt < 4; ++jt) {
                    union { uint u[4]; bf16x8 v; } bf;
                    const uint* bp = (const uint*)((const char*)&Ks[0][0]
                                     + (size_t)(jt * 16 + n) * 132 + ks * 64 + kg * 16);
                    bf.u[0] = bp[0]; bf.u[1] = bp[1]; bf.u[2] = bp[2]; bf.u[3] = bp[3];
                    st[jt] = __builtin_amdgcn_mfma_f32_16x16x32_bf16(qf[ks], bf.v, st[jt], 0, 0, 0);
                }
            }

            int mk[4];
            #pragma unroll
            for (int jt = 0; jt < 4; ++jt) mk[jt] = Msk[jt * 16 + n];

            #pragma unroll
            for (int r = 0; r < 4; ++r) {
                float mx = -1e30f;
                #pragma unroll
                for (int jt = 0; jt < 4; ++jt) {
                    float s = st[jt][r] * 0.125f;
                    if (mk[jt] == 0) s = -1e9f;
                    st[jt][r] = s;
                    mx = fmaxf(mx, s);
                }
                #pragma unroll
                for (int o = 1; o < 16; o <<= 1) mx = fmaxf(mx, __shfl_xor(mx, o, 64));
                float newm = fmaxf(m_r[r], mx);
                float alpha = __expf(m_r[r] - newm);
                m_r[r] = newm;
                float ls = 0.f;
                #pragma unroll
                for (int jt = 0; jt < 4; ++jt) {
                    float p = __expf(st[jt][r] - newm);
                    ls += p;
                    Plds[wid][kg * 4 + r][jt * 16 + n] = __float2bfloat16(p);
                }
                #pragma unroll
                for (int o = 1; o < 16; o <<= 1) ls += __shfl_xor(ls, o, 64);
                l_r[r] = l_r[r] * alpha + ls;
                #pragma unroll
                for (int dt = 0; dt < 4; ++dt) acc_o[dt][r] *= alpha;
            }

            __asm__ volatile("s_waitcnt lgkmcnt(0)" ::: "memory");

            #pragma unroll
            for (int ks = 0; ks < 2; ++ks) {
                union { uint u[4]; bf16x8 v; } af;
                const uint* ap = (const uint*)((const char*)&Plds[wid][0][0]
                                 + (size_t)n * 132 + ks * 64 + kg * 16);
                af.u[0] = ap[0]; af.u[1] = ap[1]; af.u[2] = ap[2]; af.u[3] = ap[3];
                #pragma unroll
                for (int dt = 0; dt < 4; ++dt) {
                    union { uint u[4]; bf16x8 v; } bf;
                    const uint* bp = (const uint*)((const char*)&Vt[0][0]
                                     + (size_t)(dt * 16 + n) * 132 + ks * 64 + kg * 16);
                    bf.u[0] = bp[0]; bf.u[1] = bp[1]; bf.u[2] = bp[2]; bf.u[3] = bp[3];
                    acc_o[dt] = __builtin_amdgcn_mfma_f32_16x16x32_bf16(af.v, bf.v, acc_o[dt], 0, 0, 0);
                }
            }
        }

        #pragma unroll
        for (int r = 0; r < 4; ++r) {
            float inv = (l_r[r] > 0.f) ? (1.f / l_r[r]) : 0.f;
            bf16* op = outp + ((size_t)(b * S + q0 + wid * 16 + kg * 4 + r)) * Do + h * 64 + n;
            #pragma unroll
            for (int dt = 0; dt < 4; ++dt)
                op[dt * 16] = __float2bfloat16(acc_o[dt][r] * inv);
        }
    }
}
#endif

extern "C" void kernel_launch(void* const* d_in, const int* in_sizes, int n_in,
                              void* d_out, int out_size, void* d_ws, size_t ws_size,
                              hipStream_t stream) {
    const int B = 2, S = 2048, D = 1024, H = 16, F = 4096;
    const int M = B * S;  // 4096

    const float* x   = (const float*)d_in[0];
    const int*   mask= (const int*)  d_in[1];
    const float* wq  = (const float*)d_in[2];
    const float* bq  = (const float*)d_in[3];
    const float* wk  = (const float*)d_in[4];
    const float* bk  = (const float*)d_in[5];
    const float* wv  = (const float*)d_in[6];
    const float* bv  = (const float*)d_in[7];
    const float* wo  = (const float*)d_in[8];
    const float* bo  = (const float*)d_in[9];
    const float* g1  = (const float*)d_in[10];
    const float* be1 = (const float*)d_in[11];
    const float* g2  = (const float*)d_in[12];
    const float* be2 = (const float*)d_in[13];
    const float* w1  = (const float*)d_in[14];
    const float* bf1 = (const float*)d_in[15];
    const float* w2  = (const float*)d_in[16];
    const float* bf2 = (const float*)d_in[17];
    float* out = (float*)d_out;

    char* ws = (char*)d_ws;
    const size_t MB = 1024 * 1024;
    bf16* wqkvT = (bf16*)(ws + 0 * MB);            // [3072,1024]
    bf16* woT   = (bf16*)(ws + 6 * MB);
    bf16* w1T   = (bf16*)(ws + 8 * MB);
    bf16* w2T   = (bf16*)(ws + 16 * MB);
    bf16* xn    = (bf16*)(ws + 24 * MB);
    bf16* qkv   = (bf16*)(ws + 32 * MB);           // [4096,3072]
    bf16* att   = xn;                              // reuse
    // x2 (fp32 residual carrier) lives in d_out.

    const bool fullM = (ws_size >= 64 * MB);

    transpose_all<<<12288, 256, 0, stream>>>(wq, wk, wv, wo, w1, w2,
                                             wqkvT, woT, w1T, w2T);

    ln_kernel<float><<<M, 256, 0, stream>>>(x, g1, be1, xn, D);

    gemm_mfma<128, bf16, float, false, false, true><<<dim3(3072 / 128, M / 128), 256, 0, stream>>>(
        xn, wqkvT, bq, bk, bv, (const float*)nullptr, qkv, M, 3072, D);

    attn_mfma<<<dim3(S / 128, H, B), 256, 0, stream>>>(qkv, mask, att, B, S, 3072);

    gemm_mfma<64, float, float, false, true, false><<<dim3(D / 128, M / 64), 256, 0, stream>>>(
        att, woT, bo, nullptr, nullptr, x, out, M, D, D);

    if (fullM) {
        bf16* hid = (bf16*)(ws + 24 * MB);   // [4096,4096] at [24,56)
        bf16* xn2 = (bf16*)(ws + 56 * MB);   // [4096,1024] at [56,64)
        ln_kernel<float><<<M, 256, 0, stream>>>(out, g2, be2, xn2, D);
        gemm_mfma256<true><<<dim3(F / 256, M / 256), 512, 0, stream>>>(
            xn2, w1T, bf1, hid, M, F, D);
        gemm_mfma<64, float, float, false, true, false><<<dim3(D / 128, M / 64), 256, 0, stream>>>(
            hid, w2T, bf2, nullptr, nullptr, out, out, M, D, F);
    } else {
        bf16* xn2 = (bf16*)(ws + 32 * MB);   // q-section reuse
        bf16* hid = (bf16*)(ws + 40 * MB);   // k+v sections, [2048,4096]
        const int CH = 2048;
        ln_kernel<float><<<M, 256, 0, stream>>>(out, g2, be2, xn2, D);
        for (int c = 0; c < M / CH; ++c) {
            const size_t roff = (size_t)c * CH;
            gemm_mfma<128, bf16, float, true, false, false><<<dim3(F / 128, CH / 128), 256, 0, stream>>>(
                xn2 + roff * D, w1T, bf1, nullptr, nullptr, (const float*)nullptr, hid, CH, F, D);
            gemm_mfma<64, float, float, false, true, false><<<dim3(D / 128, CH / 64), 256, 0, stream>>>(
                hid, w2T, bf2, nullptr, nullptr, out + roff * D, out + roff * D, CH, D, F);
        }
    }
}

// Round 8
// 369.541 us; speedup vs baseline: 1.1004x; 1.0305x over previous
//
#include <hip/hip_runtime.h>
#include <hip/hip_bf16.h>

// Transformer block: LN1 -> QKV -> MHA(16 heads, hd=64) -> out-proj + resid
//                    -> LN2 -> FFN(4x, ReLU) + resid
// B=2, S=2048, D=1024, H=16, hd=64, F=4096. M = B*S = 4096.
// fp32 buffers in/out; bf16 intermediates (fp32 accumulation).
//
// Round 18: round-17's K-path change eliminated ALL attn bank conflicts
// (4.19M -> 0) but dur was flat - conflicts were hidden by the
// latency-bound schedule (kept anyway: VALUBusy 47->45, VGPR 100).
// attn now runs ~790 TF (32% of peak); the GEMMs average only ~400-500 TF
// across ~294us. This round: QKV GEMM (M=4096,N=3072,K=1024) moves to the
// 256^2 4-phase gemm256 (grid 12x16=192 blocks, 75% CU fill), with BIAS3
// (q/k/v bias select) added to the gemm256 epilogue (copied from the 128^2
// kernel). Second datapoint for gemm256 at K=1024 (FFN1 gave only ~4us;
// if QKV is also flat, the 256^2 structure is exhausted at K=1024 shapes).
// Everything else unchanged from round 17.

using bf16 = __hip_bfloat16;
typedef short bf16x8 __attribute__((ext_vector_type(8)));
typedef short bf16x4v __attribute__((ext_vector_type(4)));
typedef float f32x4 __attribute__((ext_vector_type(4)));

#if defined(__has_builtin)
#  if __has_builtin(__builtin_amdgcn_mfma_f32_16x16x16bf16_1k)
#    define HAVE_MFMA_K16 1
#  endif
#  if __has_builtin(__builtin_amdgcn_exp2f)
#    define EXP2F(x) __builtin_amdgcn_exp2f(x)
#  endif
#  if __has_builtin(__builtin_amdgcn_sched_barrier)
#    define SCHED_BARRIER() __builtin_amdgcn_sched_barrier(0)
#  endif
#  if __has_builtin(__builtin_amdgcn_s_setprio)
#    define SETPRIO(x) __builtin_amdgcn_s_setprio(x)
#  endif
#endif
#ifndef EXP2F
#  define EXP2F(x) __expf(0.6931471805599453f * (x))
#endif
#ifndef SCHED_BARRIER
#  define SCHED_BARRIER()
#endif
#ifndef SETPRIO
#  define SETPRIO(x)
#endif

__device__ __forceinline__ float toF(float v) { return v; }
__device__ __forceinline__ float toF(bf16 v) { return __bfloat162float(v); }
__device__ __forceinline__ void storeF(float* p, float v) { *p = v; }
__device__ __forceinline__ void storeF(bf16* p, float v) { *p = __float2bfloat16(v); }

__device__ __forceinline__ float waveReduceSum(float v) {
    #pragma unroll
    for (int o = 32; o > 0; o >>= 1) v += __shfl_down(v, o, 64);
    return v;
}

__device__ __forceinline__ void async16(const bf16* g, bf16* l) {
    __builtin_amdgcn_global_load_lds(
        (const __attribute__((address_space(1))) unsigned int*)g,
        (__attribute__((address_space(3))) unsigned int*)l,
        16, 0, 0);
}

__device__ __forceinline__ unsigned short bf16bits(float x) {
    union { bf16 h; unsigned short u; } e; e.h = __float2bfloat16(x);
    return e.u;
}

// ---------------- fused weight transpose + cast (all 6 weights) ------------
__global__ __launch_bounds__(256) void transpose_all(
        const float* __restrict__ wq, const float* __restrict__ wk,
        const float* __restrict__ wv, const float* __restrict__ wo,
        const float* __restrict__ w1, const float* __restrict__ w2,
        bf16* __restrict__ wqkvT, bf16* __restrict__ woT,
        bf16* __restrict__ w1T, bf16* __restrict__ w2T) {
    __shared__ float t[32][33];
    const int tI = blockIdx.x;
    const float* in; bf16* outT; int R, C, tl;
    if (tI < 4096) {
        const int seg = tI >> 10; tl = tI & 1023; R = 1024; C = 1024;
        in = (seg == 0) ? wq : (seg == 1) ? wk : (seg == 2) ? wv : wo;
        outT = (seg == 3) ? woT : wqkvT + (size_t)seg * 1024 * 1024;
    } else if (tI < 8192) {
        tl = tI - 4096; in = w1; outT = w1T; R = 1024; C = 4096;
    } else {
        tl = tI - 8192; in = w2; outT = w2T; R = 4096; C = 1024;
    }
    const int tc = C >> 5;
    const int c0 = (tl % tc) * 32, r0 = (tl / tc) * 32;
    const int lx = threadIdx.x & 31, ly = threadIdx.x >> 5;
    #pragma unroll
    for (int i = 0; i < 32; i += 8)
        t[ly + i][lx] = in[(size_t)(r0 + ly + i) * C + c0 + lx];
    __syncthreads();
    #pragma unroll
    for (int i = 0; i < 32; i += 8)
        outT[(size_t)(c0 + ly + i) * R + r0 + lx] = __float2bfloat16(t[lx][ly + i]);
}

// ---------------- LayerNorm: InT x -> bf16 out ----------------
template <typename InT>
__global__ __launch_bounds__(256) void ln_kernel(const InT* __restrict__ x,
                                                 const float* __restrict__ g,
                                                 const float* __restrict__ b,
                                                 bf16* __restrict__ out, int D) {
    const int row = blockIdx.x;
    const InT* xr = x + (size_t)row * D;
    float s = 0.f, s2 = 0.f;
    for (int i = threadIdx.x; i < D; i += 256) {
        float v = toF(xr[i]);
        s += v; s2 += v * v;
    }
    __shared__ float ws[4], ws2[4];
    int lane = threadIdx.x & 63, wid = threadIdx.x >> 6;
    s = waveReduceSum(s); s2 = waveReduceSum(s2);
    if (lane == 0) { ws[wid] = s; ws2[wid] = s2; }
    __syncthreads();
    float ts = ws[0] + ws[1] + ws[2] + ws[3];
    float ts2 = ws2[0] + ws2[1] + ws2[2] + ws2[3];
    float mean = ts / D;
    float var = ts2 / D - mean * mean;
    float rstd = rsqrtf(var + 1e-5f);
    bf16* outr = out + (size_t)row * D;
    for (int i = threadIdx.x; i < D; i += 256) {
        float v = (toF(xr[i]) - mean) * rstd * g[i] + b[i];
        outr[i] = __float2bfloat16(v);
    }
}

// ---------------- MFMA GEMM: C = act(A @ BT^T + bias) [+ resid] ------------
// BK=64, XOR-swizzled LDS (chunk c of row r stored at slot c^(r&7)).
template <int BM, typename OutT, typename ResidT, bool RELU, bool HAS_RESID, bool BIAS3>
__global__ __launch_bounds__(256) void gemm_mfma(const bf16* __restrict__ A,
                                                 const bf16* __restrict__ BT,
                                                 const float* __restrict__ bias,
                                                 const float* __restrict__ biasK,
                                                 const float* __restrict__ biasV,
                                                 const ResidT* __restrict__ resid,
                                                 OutT* __restrict__ C,
                                                 int M, int N, int K) {
    constexpr int BK = 64;
    constexpr int MI = BM / 32;
    constexpr int AROWS = BM / 4;
    constexpr int ASEC = AROWS / 8;
    __shared__ bf16 As[BM][BK];      // row stride 128 B
    __shared__ bf16 Bs[128][BK];
    const int tid = threadIdx.x, lane = tid & 63, wid = tid >> 6;
    const int m0 = blockIdx.y * BM, n0 = blockIdx.x * 128;
    const int wm = (BM == 128) ? (wid >> 1) * 64 : (wid & 1) * 32;
    const int wn = (BM == 128) ? (wid & 1) * 64 : (wid >> 1) * 64;

    f32x4 acc[MI][4] = {};

    const int srow = lane >> 3;
    const int scol = ((lane & 7) ^ srow) * 8;
    const bf16* Abase = A + (size_t)(m0 + wid * AROWS + srow) * K + scol;
    const bf16* Bbase = BT + (size_t)(n0 + wid * 32 + srow) * K + scol;

    const int fr = lane & 15;
    const int kg = lane >> 4;

    for (int k0 = 0; k0 < K; k0 += BK) {
        #pragma unroll
        for (int s = 0; s < ASEC; ++s)
            async16(Abase + (size_t)(s * 8) * K + k0, &As[wid * AROWS + s * 8][0]);
        #pragma unroll
        for (int s = 0; s < 4; ++s)
            async16(Bbase + (size_t)(s * 8) * K + k0, &Bs[wid * 32 + s * 8][0]);
        __syncthreads();

        #pragma unroll
        for (int ks = 0; ks < 2; ++ks) {
            const int pc = ((ks * 4 + kg) ^ (fr & 7)) * 16;
            bf16x8 aF[MI], bF[4];
            #pragma unroll
            for (int i = 0; i < MI; ++i)
                aF[i] = *(const bf16x8*)((const char*)&As[0][0]
                         + (size_t)(wm + i * 16 + fr) * 128 + pc);
            #pragma unroll
            for (int j = 0; j < 4; ++j)
                bF[j] = *(const bf16x8*)((const char*)&Bs[0][0]
                         + (size_t)(wn + j * 16 + fr) * 128 + pc);
            #pragma unroll
            for (int i = 0; i < MI; ++i)
                #pragma unroll
                for (int j = 0; j < 4; ++j)
                    acc[i][j] = __builtin_amdgcn_mfma_f32_16x16x32_bf16(
                        aF[i], bF[j], acc[i][j], 0, 0, 0);
        }
        __syncthreads();
    }

    const int col_l = lane & 15, row_l = (lane >> 4) * 4;
    #pragma unroll
    for (int j = 0; j < 4; ++j) {
        const int col = n0 + wn + j * 16 + col_l;
        float bvv;
        if (BIAS3) {
            const float* bp = (col < 1024) ? bias : ((col < 2048) ? biasK : biasV);
            bvv = bp[col & 1023];
        } else {
            bvv = bias[col];
        }
        #pragma unroll
        for (int i = 0; i < MI; ++i) {
            #pragma unroll
            for (int r = 0; r < 4; ++r) {
                const int row = m0 + wm + i * 16 + row_l + r;
                float v = acc[i][j][r] + bvv;
                if (RELU) v = fmaxf(v, 0.f);
                if (HAS_RESID) v += toF(resid[(size_t)row * N + col]);
                storeF(&C[(size_t)row * N + col], v);
            }
        }
    }
}

// ---------------- 256x256 8-phase MFMA GEMM (T2+T3+T4+T5) ------------------
// 512 threads / 8 waves (2M x 4N); per-wave output 128x64; BK=64.
// Double-buffered 128KB LDS; 4 phases per K-tile; counted vmcnt (drain only
// at phase 3, for stages issued >=2 phases earlier); raw s_barrier; setprio
// around each 16-MFMA cluster. BIAS3: q/k/v bias select (col/1024).
template <bool RELU, bool BIAS3>
__global__ __launch_bounds__(512, 1) void gemm_mfma256(const bf16* __restrict__ A,
                                                       const bf16* __restrict__ BT,
                                                       const float* __restrict__ bias,
                                                       const float* __restrict__ biasK,
                                                       const float* __restrict__ biasV,
                                                       bf16* __restrict__ C,
                                                       int M, int N, int K) {
    constexpr int BK = 64;
    __shared__ bf16 As[2][256][BK];
    __shared__ bf16 Bs[2][256][BK];
    const int tid = threadIdx.x, lane = tid & 63, wid = tid >> 6;
    const int m0 = blockIdx.y * 256, n0 = blockIdx.x * 256;
    const int wm = (wid >> 2) * 128, wn = (wid & 3) * 64;

    f32x4 acc[8][4] = {};

    const int srow = lane >> 3;
    const int scol = ((lane & 7) ^ srow) * 8;   // pre-swizzled source chunk
    const bf16* Abase = A + (size_t)(m0 + wid * 16 + srow) * K + scol;
    const bf16* Bbase = BT + (size_t)(n0 + wid * 16 + srow) * K + scol;

    const int fr = lane & 15;
    const int kg = lane >> 4;
    const int NT = K / BK;

    // prologue: stage tile 0 into buf 0
    #pragma unroll
    for (int h = 0; h < 2; ++h)
        #pragma unroll
        for (int s = 0; s < 2; ++s) {
            async16(Abase + (size_t)(h * 128 + s * 8) * K,
                    &As[0][h * 128 + wid * 16 + s * 8][0]);
            async16(Bbase + (size_t)(h * 128 + s * 8) * K,
                    &Bs[0][h * 128 + wid * 16 + s * 8][0]);
        }
    asm volatile("s_waitcnt vmcnt(0)" ::: "memory");
    __builtin_amdgcn_s_barrier();
    SCHED_BARRIER();

    for (int t = 0; t < NT; ++t) {
        const int cur = t & 1;
        const size_t k1 = (size_t)(t + 1) * BK;
        const char* ab = (const char*)&As[cur][0][0];
        const char* bb = (const char*)&Bs[cur][0][0];
        const bool pf = (t + 1 < NT);
        bf16x8 aF[4][2], bF[4][2];

        // ---- phase 0: read A rows0-3 + B cols0-1; stage next A ----
        #pragma unroll
        for (int i = 0; i < 4; ++i)
            #pragma unroll
            for (int kk = 0; kk < 2; ++kk)
                aF[i][kk] = *(const bf16x8*)(ab + (size_t)(wm + i * 16 + fr) * 128
                                             + ((kk * 4 + kg) ^ (fr & 7)) * 16);
        #pragma unroll
        for (int j = 0; j < 2; ++j)
            #pragma unroll
            for (int kk = 0; kk < 2; ++kk)
                bF[j][kk] = *(const bf16x8*)(bb + (size_t)(wn + j * 16 + fr) * 128
                                             + ((kk * 4 + kg) ^ (fr & 7)) * 16);
        if (pf) {
            #pragma unroll
            for (int h = 0; h < 2; ++h)
                #pragma unroll
                for (int s = 0; s < 2; ++s)
                    async16(Abase + (size_t)(h * 128 + s * 8) * K + k1,
                            &As[cur ^ 1][h * 128 + wid * 16 + s * 8][0]);
        }
        __builtin_amdgcn_s_barrier();
        SCHED_BARRIER();
        SETPRIO(1);
        #pragma unroll
        for (int i = 0; i < 4; ++i)
            #pragma unroll
            for (int j = 0; j < 2; ++j)
                #pragma unroll
                for (int kk = 0; kk < 2; ++kk)
                    acc[i][j] = __builtin_amdgcn_mfma_f32_16x16x32_bf16(
                        aF[i][kk], bF[j][kk], acc[i][j], 0, 0, 0);
        SETPRIO(0);

        // ---- phase 1: read B cols2-3; stage next B ----
        #pragma unroll
        for (int j = 2; j < 4; ++j)
            #pragma unroll
            for (int kk = 0; kk < 2; ++kk)
                bF[j][kk] = *(const bf16x8*)(bb + (size_t)(wn + j * 16 + fr) * 128
                                             + ((kk * 4 + kg) ^ (fr & 7)) * 16);
        if (pf) {
            #pragma unroll
            for (int h = 0; h < 2; ++h)
                #pragma unroll
                for (int s = 0; s < 2; ++s)
                    async16(Bbase + (size_t)(h * 128 + s * 8) * K + k1,
                            &Bs[cur ^ 1][h * 128 + wid * 16 + s * 8][0]);
        }
        __builtin_amdgcn_s_barrier();
        SCHED_BARRIER();
        SETPRIO(1);
        #pragma unroll
        for (int i = 0; i < 4; ++i)
            #pragma unroll
            for (int j = 2; j < 4; ++j)
                #pragma unroll
                for (int kk = 0; kk < 2; ++kk)
                    acc[i][j] = __builtin_amdgcn_mfma_f32_16x16x32_bf16(
                        aF[i][kk], bF[j][kk], acc[i][j], 0, 0, 0);
        SETPRIO(0);

        // ---- phase 2: read A rows4-7 (reuse aF regs) ----
        #pragma unroll
        for (int i = 0; i < 4; ++i)
            #pragma unroll
            for (int kk = 0; kk < 2; ++kk)
                aF[i][kk] = *(const bf16x8*)(ab + (size_t)(wm + (i + 4) * 16 + fr) * 128
                                             + ((kk * 4 + kg) ^ (fr & 7)) * 16);
        __builtin_amdgcn_s_barrier();
        SCHED_BARRIER();
        SETPRIO(1);
        #pragma unroll
        for (int i = 0; i < 4; ++i)
            #pragma unroll
            for (int j = 0; j < 2; ++j)
                #pragma unroll
                for (int kk = 0; kk < 2; ++kk)
                    acc[i + 4][j] = __builtin_amdgcn_mfma_f32_16x16x32_bf16(
                        aF[i][kk], bF[j][kk], acc[i + 4][j], 0, 0, 0);
        SETPRIO(0);

        // ---- phase 3: publish next tile (vmcnt for stages issued in ph0/1) -
        if (pf) asm volatile("s_waitcnt vmcnt(0)" ::: "memory");
        __builtin_amdgcn_s_barrier();
        SCHED_BARRIER();
        SETPRIO(1);
        #pragma unroll
        for (int i = 0; i < 4; ++i)
            #pragma unroll
            for (int j = 2; j < 4; ++j)
                #pragma unroll
                for (int kk = 0; kk < 2; ++kk)
                    acc[i + 4][j] = __builtin_amdgcn_mfma_f32_16x16x32_bf16(
                        aF[i][kk], bF[j][kk], acc[i + 4][j], 0, 0, 0);
        SETPRIO(0);
    }

    // ---- epilogue: bias (+ReLU), bf16 store ----
    const int col_l = lane & 15, row_l = (lane >> 4) * 4;
    #pragma unroll
    for (int j = 0; j < 4; ++j) {
        const int col = n0 + wn + j * 16 + col_l;
        float bvv;
        if (BIAS3) {
            const float* bp = (col < 1024) ? bias : ((col < 2048) ? biasK : biasV);
            bvv = bp[col & 1023];
        } else {
            bvv = bias[col];
        }
        #pragma unroll
        for (int i = 0; i < 8; ++i) {
            #pragma unroll
            for (int r = 0; r < 4; ++r) {
                const int row = m0 + wm + i * 16 + row_l + r;
                float v = acc[i][j][r] + bvv;
                if (RELU) v = fmaxf(v, 0.f);
                C[(size_t)row * N + col] = __float2bfloat16(v);
            }
        }
    }
}

// ---------------- MFMA flash attention, S^T formulation, TQ=128 ------------
// Round-12 logic; round-17 K-path: K staged via async16 (global_load_lds)
// into linear [64][64] Ks with GEMM-style XOR chunk swizzle; K-frag reads
// are single ds_read_b128. V keeps reg-staged transpose (T14).
#if HAVE_MFMA_K16
__global__ __launch_bounds__(256) void attn_mfma(const bf16* __restrict__ qkv,
                                                 const int* __restrict__ mask,
                                                 bf16* __restrict__ outp,
                                                 int B, int S, int LD) {
    const int q0 = blockIdx.x * 128;
    const int h = blockIdx.y, b = blockIdx.z;
    const int Do = 1024;
    const int tid = threadIdx.x, lane = tid & 63, wid = tid >> 6;
    const int n = lane & 15, kg = lane >> 4;

    __shared__ bf16 Ks[2][64][64];   // K tile [j][d], 128B rows, XOR chunks
    __shared__ bf16 Vt[2][64][68];   // V^T tile [d][j], 136B rows
    __shared__ float Mskf[2][64];    // additive mask bias (log2 domain)
    __shared__ int sAny[2];          // any masked position in this j-tile?

    // Q B-frags, pre-scaled by (1/sqrt(64))*log2(e); wave owns 32 q-rows.
    const float QSCALE = 0.125f * 1.4426950408889634f;
    bf16x8 qf[2][2];
    #pragma unroll
    for (int u = 0; u < 2; ++u) {
        const bf16* qp = qkv + ((size_t)(b * S + q0 + wid * 32 + u * 16 + n)) * LD + h * 64 + kg * 8;
        union { uint4 uu; bf16x8 v; unsigned short s[8]; } c[2];
        c[0].uu = *(const uint4*)qp;
        c[1].uu = *(const uint4*)(qp + 32);
        #pragma unroll
        for (int t = 0; t < 2; ++t) {
            #pragma unroll
            for (int i = 0; i < 8; ++i) {
                union { float f; unsigned int u2; } d;
                d.u2 = ((unsigned int)c[t].s[i]) << 16;
                c[t].s[i] = bf16bits(d.f * QSCALE);
            }
            qf[u][t] = c[t].v;
        }
    }

    f32x4 acc[2][4] = {};
    float m[2] = {-1e30f, -1e30f}, l[2] = {0.f, 0.f};

    const int jp = tid & 31, dg = (tid >> 5) * 8;
    const bf16* kbase = qkv + (size_t)(b * S) * LD + 1024 + h * 64;
    const bf16* vbase = qkv + (size_t)(b * S) * LD + 2048 + h * 64;

    // K async staging: pre-swizzled per-lane global source (GEMM pattern).
    const int srow = lane >> 3;
    const int scol = ((lane & 7) ^ srow) * 8;
    const bf16* kAsy = kbase + (size_t)(wid * 16 + srow) * LD + scol;

    // staged V registers (T14 issue-early / write-late)
    uint4 vau, vcu;
    int mz = 0;

    // prologue: K tile-0 async -> Ks[0]; V tile-0 + mask -> regs
    {
        #pragma unroll
        for (int s = 0; s < 2; ++s)
            async16(kAsy + (size_t)(s * 8) * LD, &Ks[0][wid * 16 + s * 8][0]);
        const bf16* vp = vbase + (size_t)(2 * jp) * LD + dg;
        vau = *(const uint4*)vp;
        vcu = *(const uint4*)(vp + LD);
        if (tid < 64) mz = (mask[b * S + tid] == 0);
    }

    const int NT = S / 64;
    for (int t = 0; t < NT; ++t) {
        const int cur = t & 1;

        // ---- write staged V tile t into LDS buf[cur]; mask bias ----
        {
            union { uint4 u4; unsigned short s[8]; } va, vc;
            va.u4 = vau; vc.u4 = vcu;
            #pragma unroll
            for (int i = 0; i < 8; ++i) {
                unsigned int pk = (unsigned int)va.s[i] | ((unsigned int)vc.s[i] << 16);
                *(unsigned int*)((char*)&Vt[cur][0][0] + (size_t)(dg + i) * 136 + jp * 4) = pk;
            }
            if (tid < 64) {
                Mskf[cur][tid] = mz ? -1e9f : 0.f;
                unsigned long long bl = __ballot(mz);
                if (tid == 0) sAny[cur] = (bl != 0ull) ? 1 : 0;
            }
        }
        // __syncthreads lowers to s_waitcnt vmcnt(0) lgkmcnt(0); s_barrier:
        // drains this buffer's K-asyncs block-wide before any wave reads Ks[cur].
        __syncthreads();

        // ---- issue tile t+1: K async -> Ks[cur^1]; V + mask -> regs -------
        if (t + 1 < NT) {
            const int j0 = (t + 1) * 64;
            #pragma unroll
            for (int s = 0; s < 2; ++s)
                async16(kAsy + (size_t)(j0 + s * 8) * LD, &Ks[cur ^ 1][wid * 16 + s * 8][0]);
            const bf16* vp = vbase + (size_t)(j0 + 2 * jp) * LD + dg;
            vau = *(const uint4*)vp;
            vcu = *(const uint4*)(vp + LD);
            if (tid < 64) mz = (mask[b * S + j0 + tid] == 0);
        }

        // ---- S^T = K @ Q^T (log2-scaled); K-frags: 1x ds_read_b128 each ---
        f32x4 st[2][4] = {};
        #pragma unroll
        for (int ks = 0; ks < 2; ++ks) {
            #pragma unroll
            for (int jt = 0; jt < 4; ++jt) {
                bf16x8 kf = *(const bf16x8*)((const char*)&Ks[cur][0][0]
                             + (size_t)(jt * 16 + n) * 128
                             + (size_t)(((ks * 4 + kg) ^ (n & 7)) * 16));
                st[0][jt] = __builtin_amdgcn_mfma_f32_16x16x32_bf16(kf, qf[0][ks], st[0][jt], 0, 0, 0);
                st[1][jt] = __builtin_amdgcn_mfma_f32_16x16x32_bf16(kf, qf[1][ks], st[1][jt], 0, 0, 0);
            }
        }

        // ---- mask bias only when the tile actually has masked positions ---
        if (sAny[cur]) {
            #pragma unroll
            for (int u = 0; u < 2; ++u) {
                #pragma unroll
                for (int jt = 0; jt < 4; ++jt) {
                    f32x4 mb = *(const f32x4*)&Mskf[cur][jt * 16 + kg * 4];
                    #pragma unroll
                    for (int r = 0; r < 4; ++r) st[u][jt][r] += mb[r];
                }
            }
        }

        // ---- online softmax with defer-max (THR=8 in log2 domain) ---------
        float mx0 = st[0][0][0], mx1 = st[1][0][0];
        #pragma unroll
        for (int jt = 0; jt < 4; ++jt) {
            #pragma unroll
            for (int r = 0; r < 4; ++r) {
                mx0 = fmaxf(mx0, st[0][jt][r]);
                mx1 = fmaxf(mx1, st[1][jt][r]);
            }
        }
        mx0 = fmaxf(mx0, __shfl_xor(mx0, 16, 64));
        mx0 = fmaxf(mx0, __shfl_xor(mx0, 32, 64));
        mx1 = fmaxf(mx1, __shfl_xor(mx1, 16, 64));
        mx1 = fmaxf(mx1, __shfl_xor(mx1, 32, 64));

        if (__any((mx0 > m[0] + 8.f) || (mx1 > m[1] + 8.f))) {
            float mxa[2] = {mx0, mx1};
            #pragma unroll
            for (int u = 0; u < 2; ++u) {
                float newm = fmaxf(m[u], mxa[u]);
                float alpha = EXP2F(m[u] - newm);
                m[u] = newm;
                l[u] *= alpha;
                #pragma unroll
                for (int dt = 0; dt < 4; ++dt)
                    #pragma unroll
                    for (int r = 0; r < 4; ++r) acc[u][dt][r] *= alpha;
            }
        }

        bf16x4v pf[2][4];
        #pragma unroll
        for (int u = 0; u < 2; ++u) {
            float ls = 0.f;
            #pragma unroll
            for (int jt = 0; jt < 4; ++jt) {
                union { unsigned short s[4]; bf16x4v v; } pk;
                #pragma unroll
                for (int r = 0; r < 4; ++r) {
                    union { float f; unsigned int u2; } p;
                    p.f = EXP2F(st[u][jt][r] - m[u]);
                    p.u2 &= 0xffff0000u;          // truncate to bf16
                    ls += p.f;                    // sum the truncated value
                    pk.s[r] = (unsigned short)(p.u2 >> 16);
                }
                pf[u][jt] = pk.v;
            }
            ls += __shfl_xor(ls, 16, 64);
            ls += __shfl_xor(ls, 32, 64);
            l[u] += ls;
        }

        // ---- O^T += V^T @ P^T; V-frags read once ----
        #pragma unroll
        for (int jt = 0; jt < 4; ++jt) {
            #pragma unroll
            for (int dt = 0; dt < 4; ++dt) {
                union { uint u[2]; bf16x4v v; } vf;
                const uint* vpp = (const uint*)((const char*)&Vt[cur][0][0]
                                  + (size_t)(dt * 16 + n) * 136 + jt * 32 + kg * 8);
                vf.u[0] = vpp[0]; vf.u[1] = vpp[1];
                acc[0][dt] = __builtin_amdgcn_mfma_f32_16x16x16bf16_1k(vf.v, pf[0][jt], acc[0][dt], 0, 0, 0);
                acc[1][dt] = __builtin_amdgcn_mfma_f32_16x16x16bf16_1k(vf.v, pf[1][jt], acc[1][dt], 0, 0, 0);
            }
        }
    }

    // ---- epilogue ----
    #pragma unroll
    for (int u = 0; u < 2; ++u) {
        float inv = (l[u] > 0.f) ? (1.f / l[u]) : 0.f;
        bf16* op = outp + ((size_t)(b * S + q0 + wid * 32 + u * 16 + n)) * Do + h * 64;
        #pragma unroll
        for (int dt = 0; dt < 4; ++dt) {
            union { unsigned short s[4]; uint2 u2; } w;
            #pragma unroll
            for (int r = 0; r < 4; ++r) w.s[r] = bf16bits(acc[u][dt][r] * inv);
            *(uint2*)(op + dt * 16 + kg * 4) = w.u2;
        }
    }
}
#else
// Fallback (round-5 structure); handles 128 q-rows as two sequential halves.
__global__ __launch_bounds__(256) void attn_mfma(const bf16* __restrict__ qkv,
                                                 const int* __restrict__ mask,
                                                 bf16* __restrict__ outp,
                                                 int B, int S, int LD) {
    const int h = blockIdx.y, b = blockIdx.z;
    const int Do = 1024;
    const int tid = threadIdx.x, lane = tid & 63, wid = tid >> 6;
    const int n = lane & 15, kg = lane >> 4;

    __shared__ bf16 Ks[64][66];
    __shared__ bf16 Vt[64][66];
    __shared__ bf16 Plds[4][16][66];
    __shared__ int  Msk[64];

    for (int half = 0; half < 2; ++half) {
        const int q0 = blockIdx.x * 128 + half * 64;
        __syncthreads();

        bf16x8 qf[2];
        {
            const bf16* qp = qkv + ((size_t)(b * S + q0 + wid * 16 + n)) * LD + h * 64 + kg * 8;
            union { uint4 u; bf16x8 v; } c0, c1;
            c0.u = *(const uint4*)qp;
            c1.u = *(const uint4*)(qp + 32);
            qf[0] = c0.v; qf[1] = c1.v;
        }

        f32x4 acc_o[4] = {};
        float m_r[4] = {-1e30f, -1e30f, -1e30f, -1e30f};
        float l_r[4] = {0.f, 0.f, 0.f, 0.f};

        const int sr = tid >> 2;
        const int sc = (tid & 3) * 16;
        const bf16* kbase = qkv + (size_t)(b * S) * LD + 1024 + h * 64;
        const bf16* vbase = qkv + (size_t)(b * S) * LD + 2048 + h * 64;

        for (int j0 = 0; j0 < S; j0 += 64) {
            __syncthreads();
            {
                const bf16* kp = kbase + (size_t)(j0 + sr) * LD + sc;
                uint4 ka = *(const uint4*)kp;
                uint4 kbv = *(const uint4*)(kp + 8);
                uint* kd = (uint*)((char*)&Ks[0][0] + sr * 132 + sc * 2);
                kd[0] = ka.x; kd[1] = ka.y; kd[2] = ka.z; kd[3] = ka.w;
                kd[4] = kbv.x; kd[5] = kbv.y; kd[6] = kbv.z; kd[7] = kbv.w;

                const bf16* vp = vbase + (size_t)(j0 + sr) * LD + sc;
                union { uint4 u[2]; unsigned short s[16]; } vv;
                vv.u[0] = *(const uint4*)vp;
                vv.u[1] = *(const uint4*)(vp + 8);
                #pragma unroll
                for (int i = 0; i < 16; ++i)
                    *((unsigned short*)((char*)&Vt[0][0] + (size_t)(sc + i) * 132 + sr * 2)) = vv.s[i];

                if (tid < 64) Msk[tid] = mask[b * S + j0 + tid];
            }
            __syncthreads();

            f32x4 st[4] = {};
            #pragma unroll
            for (int ks = 0; ks < 2; ++ks) {
                #pragma unroll
                for (int jt = 0; jt < 4; ++jt) {
                    union { uint u[4]; bf16x8 v; } bf;
                    const uint* bp = (const uint*)((const char*)&Ks[0][0]
                                     + (size_t)(jt * 16 + n) * 132 + ks * 64 + kg * 16);
                    bf.u[0] = bp[0]; bf.u[1] = bp[1]; bf.u[2] = bp[2]; bf.u[3] = bp[3];
                    st[jt] = __builtin_amdgcn_mfma_f32_16x16x32_bf16(qf[ks], bf.v, st[jt], 0, 0, 0);
                }
            }

            int mk[4];
            #pragma unroll
            for (int jt = 0; jt < 4; ++jt) mk[jt] = Msk[jt * 16 + n];

            #pragma unroll
            for (int r = 0; r < 4; ++r) {
                float mx = -1e30f;
                #pragma unroll
                for (int jt = 0; jt < 4; ++jt) {
                    float s = st[jt][r] * 0.125f;
                    if (mk[jt] == 0) s = -1e9f;
                    st[jt][r] = s;
                    mx = fmaxf(mx, s);
                }
                #pragma unroll
                for (int o = 1; o < 16; o <<= 1) mx = fmaxf(mx, __shfl_xor(mx, o, 64));
                float newm = fmaxf(m_r[r], mx);
                float alpha = __expf(m_r[r] - newm);
                m_r[r] = newm;
                float ls = 0.f;
                #pragma unroll
                for (int jt = 0; jt < 4; ++jt) {
                    float p = __expf(st[jt][r] - newm);
                    ls += p;
                    Plds[wid][kg * 4 + r][jt * 16 + n] = __float2bfloat16(p);
                }
                #pragma unroll
                for (int o = 1; o < 16; o <<= 1) ls += __shfl_xor(ls, o, 64);
                l_r[r] = l_r[r] * alpha + ls;
                #pragma unroll
                for (int dt = 0; dt < 4; ++dt) acc_o[dt][r] *= alpha;
            }

            __asm__ volatile("s_waitcnt lgkmcnt(0)" ::: "memory");

            #pragma unroll
            for (int ks = 0; ks < 2; ++ks) {
                union { uint u[4]; bf16x8 v; } af;
                const uint* ap = (const uint*)((const char*)&Plds[wid][0][0]
                                 + (size_t)n * 132 + ks * 64 + kg * 16);
                af.u[0] = ap[0]; af.u[1] = ap[1]; af.u[2] = ap[2]; af.u[3] = ap[3];
                #pragma unroll
                for (int dt = 0; dt < 4; ++dt) {
                    union { uint u[4]; bf16x8 v; } bf;
                    const uint* bp = (const uint*)((const char*)&Vt[0][0]
                                     + (size_t)(dt * 16 + n) * 132 + ks * 64 + kg * 16);
                    bf.u[0] = bp[0]; bf.u[1] = bp[1]; bf.u[2] = bp[2]; bf.u[3] = bp[3];
                    acc_o[dt] = __builtin_amdgcn_mfma_f32_16x16x32_bf16(af.v, bf.v, acc_o[dt], 0, 0, 0);
                }
            }
        }

        #pragma unroll
        for (int r = 0; r < 4; ++r) {
            float inv = (l_r[r] > 0.f) ? (1.f / l_r[r]) : 0.f;
            bf16* op = outp + ((size_t)(b * S + q0 + wid * 16 + kg * 4 + r)) * Do + h * 64 + n;
            #pragma unroll
            for (int dt = 0; dt < 4; ++dt)
                op[dt * 16] = __float2bfloat16(acc_o[dt][r] * inv);
        }
    }
}
#endif

extern "C" void kernel_launch(void* const* d_in, const int* in_sizes, int n_in,
                              void* d_out, int out_size, void* d_ws, size_t ws_size,
                              hipStream_t stream) {
    const int B = 2, S = 2048, D = 1024, H = 16, F = 4096;
    const int M = B * S;  // 4096

    const float* x   = (const float*)d_in[0];
    const int*   mask= (const int*)  d_in[1];
    const float* wq  = (const float*)d_in[2];
    const float* bq  = (const float*)d_in[3];
    const float* wk  = (const float*)d_in[4];
    const float* bk  = (const float*)d_in[5];
    const float* wv  = (const float*)d_in[6];
    const float* bv  = (const float*)d_in[7];
    const float* wo  = (const float*)d_in[8];
    const float* bo  = (const float*)d_in[9];
    const float* g1  = (const float*)d_in[10];
    const float* be1 = (const float*)d_in[11];
    const float* g2  = (const float*)d_in[12];
    const float* be2 = (const float*)d_in[13];
    const float* w1  = (const float*)d_in[14];
    const float* bf1 = (const float*)d_in[15];
    const float* w2  = (const float*)d_in[16];
    const float* bf2 = (const float*)d_in[17];
    float* out = (float*)d_out;

    char* ws = (char*)d_ws;
    const size_t MB = 1024 * 1024;
    bf16* wqkvT = (bf16*)(ws + 0 * MB);            // [3072,1024]
    bf16* woT   = (bf16*)(ws + 6 * MB);
    bf16* w1T   = (bf16*)(ws + 8 * MB);
    bf16* w2T   = (bf16*)(ws + 16 * MB);
    bf16* xn    = (bf16*)(ws + 24 * MB);
    bf16* qkv   = (bf16*)(ws + 32 * MB);           // [4096,3072]
    bf16* att   = xn;                              // reuse
    // x2 (fp32 residual carrier) lives in d_out.

    const bool fullM = (ws_size >= 64 * MB);

    transpose_all<<<12288, 256, 0, stream>>>(wq, wk, wv, wo, w1, w2,
                                             wqkvT, woT, w1T, w2T);

    ln_kernel<float><<<M, 256, 0, stream>>>(x, g1, be1, xn, D);

    gemm_mfma256<false, true><<<dim3(3072 / 256, M / 256), 512, 0, stream>>>(
        xn, wqkvT, bq, bk, bv, qkv, M, 3072, D);

    attn_mfma<<<dim3(S / 128, H, B), 256, 0, stream>>>(qkv, mask, att, B, S, 3072);

    gemm_mfma<64, float, float, false, true, false><<<dim3(D / 128, M / 64), 256, 0, stream>>>(
        att, woT, bo, nullptr, nullptr, x, out, M, D, D);

    if (fullM) {
        bf16* hid = (bf16*)(ws + 24 * MB);   // [4096,4096] at [24,56)
        bf16* xn2 = (bf16*)(ws + 56 * MB);   // [4096,1024] at [56,64)
        ln_kernel<float><<<M, 256, 0, stream>>>(out, g2, be2, xn2, D);
        gemm_mfma256<true, false><<<dim3(F / 256, M / 256), 512, 0, stream>>>(
            xn2, w1T, bf1, nullptr, nullptr, hid, M, F, D);
        gemm_mfma<64, float, float, false, true, false><<<dim3(D / 128, M / 64), 256, 0, stream>>>(
            hid, w2T, bf2, nullptr, nullptr, out, out, M, D, F);
    } else {
        bf16* xn2 = (bf16*)(ws + 32 * MB);   // q-section reuse
        bf16* hid = (bf16*)(ws + 40 * MB);   // k+v sections, [2048,4096]
        const int CH = 2048;
        ln_kernel<float><<<M, 256, 0, stream>>>(out, g2, be2, xn2, D);
        for (int c = 0; c < M / CH; ++c) {
            const size_t roff = (size_t)c * CH;
            gemm_mfma<128, bf16, float, true, false, false><<<dim3(F / 128, CH / 128), 256, 0, stream>>>(
                xn2 + roff * D, w1T, bf1, nullptr, nullptr, (const float*)nullptr, hid, CH, F, D);
            gemm_mfma<64, float, float, false, true, false><<<dim3(D / 128, CH / 64), 256, 0, stream>>>(
                hid, w2T, bf2, nullptr, nullptr, out + roff * D, out + roff * D, CH, D, F);
        }
    }
}